// Round 1
// baseline (9395.038 us; speedup 1.0000x reference)
//
#include <hip/hip_runtime.h>
#include <math.h>

#define WT 64
#define NWIN 1344
constexpr float SCALE = 0.088388347648318447f;  // 128^-0.5

// out region offsets (floats)
#define OUT0 0
#define OUT1 2097152
#define OUT2 10485760

__device__ __forceinline__ void fma4(float4& a, float s, const float4 b) {
    a.x += s * b.x; a.y += s * b.y; a.z += s * b.z; a.w += s * b.w;
}
__device__ __forceinline__ float dot4(const float4 a, const float4 b) {
    return a.x * b.x + a.y * b.y + a.z * b.z + a.w * b.w;
}

// K1: Mloc = Wql @ Wkl^T, Mglob = Wq @ Wk^T  (tiny)
__global__ void k_mm(const float* __restrict__ Wql, const float* __restrict__ Wkl,
                     const float* __restrict__ Wq, const float* __restrict__ Wk,
                     float* __restrict__ Mloc, float* __restrict__ Mglob) {
    int i = blockIdx.x, j = threadIdx.x;
    const float* A = blockIdx.y ? Wq : Wql;
    const float* Bm = blockIdx.y ? Wk : Wkl;
    float* O = blockIdx.y ? Mglob : Mloc;
    float acc = 0.f;
    for (int k = 0; k < 128; ++k) acc += A[i * 128 + k] * Bm[j * 128 + k];
    O[i * 128 + j] = acc;
}

__device__ __forceinline__ void window_src(int n0, const float* f0, const float* f1,
                                           const float* f2, const float*& f, int& p0,
                                           int& HW, int& obase) {
    if (n0 < 4096)        { f = f0; p0 = n0;          HW = 4096;  obase = OUT0; }
    else if (n0 < 20480)  { f = f1; p0 = n0 - 4096;   HW = 16384; obase = OUT1; }
    else                  { f = f2; p0 = n0 - 20480;  HW = 65536; obase = OUT2; }
}

// K2: window means -> centers [B,NWIN,128]
__global__ __launch_bounds__(256) void k_centers(
    const float* __restrict__ f0, const float* __restrict__ f1,
    const float* __restrict__ f2, float* __restrict__ ctr) {
    int w = blockIdx.x, b = blockIdx.y;
    const float* f; int p0, HW, ob;
    window_src(w * WT, f0, f1, f2, f, p0, HW, ob);
    int lane = threadIdx.x & 63, cg = threadIdx.x >> 6;
    for (int c = cg; c < 128; c += 4) {
        float v = f[(b * 128 + c) * HW + p0 + lane];
        #pragma unroll
        for (int off = 32; off; off >>= 1) v += __shfl_xor(v, off);
        if (lane == 0) ctr[(b * NWIN + w) * 128 + c] = v * (1.0f / 64.0f);
    }
}

// K3: Tg = centers @ Mglob ; Vg = centers @ Wv
__global__ __launch_bounds__(128) void k_tgvg(
    const float* __restrict__ ctr, const float* __restrict__ Mglob,
    const float* __restrict__ Wv, float* __restrict__ Tg, float* __restrict__ Vg) {
    int row = blockIdx.y * NWIN + blockIdx.x;
    int c = threadIdx.x;
    __shared__ __align__(16) float crow[128];
    crow[c] = ctr[row * 128 + c];
    __syncthreads();
    float a1 = 0.f, a2 = 0.f;
    for (int k = 0; k < 128; ++k) {
        float cv = crow[k];
        a1 += cv * Mglob[k * 128 + c];
        a2 += cv * Wv[k * 128 + c];
    }
    Tg[row * 128 + c] = a1;
    Vg[row * 128 + c] = a2;
}

// K4: global attention over 1344 window-centers; ycen = (attn @ Vg) * centers
__global__ __launch_bounds__(256) void k_gattn(
    const float* __restrict__ ctr, const float* __restrict__ Tg,
    const float* __restrict__ Vg, float* __restrict__ ycen) {
    int w = blockIdx.x, b = blockIdx.y;
    int row = b * NWIN + w;
    __shared__ __align__(16) float sc[NWIN];
    __shared__ __align__(16) float Trow[128];
    __shared__ float red[4];
    __shared__ float part[256];
    int tid = threadIdx.x;
    if (tid < 128) Trow[tid] = Tg[row * 128 + tid];
    __syncthreads();
    int quad = tid >> 2, qq = tid & 3;
    const float4* T4 = (const float4*)Trow;
    float lmax = -1e30f;
    for (int k = quad; k < NWIN; k += 64) {
        const float4* C4 = (const float4*)(ctr + (b * NWIN + k) * 128);
        float s = 0.f;
        #pragma unroll
        for (int j = 0; j < 8; ++j) s += dot4(T4[qq * 8 + j], C4[qq * 8 + j]);
        s += __shfl_xor(s, 1);
        s += __shfl_xor(s, 2);
        s *= SCALE;
        if (qq == 0) sc[k] = s;
        lmax = fmaxf(lmax, s);
    }
    #pragma unroll
    for (int off = 32; off; off >>= 1) lmax = fmaxf(lmax, __shfl_xor(lmax, off));
    if ((tid & 63) == 0) red[tid >> 6] = lmax;
    __syncthreads();
    float bmax = fmaxf(fmaxf(red[0], red[1]), fmaxf(red[2], red[3]));
    __syncthreads();
    float lsum = 0.f;
    for (int k = tid; k < NWIN; k += 256) {
        float e = __expf(sc[k] - bmax);
        sc[k] = e;
        lsum += e;
    }
    #pragma unroll
    for (int off = 32; off; off >>= 1) lsum += __shfl_xor(lsum, off);
    if ((tid & 63) == 0) red[tid >> 6] = lsum;
    __syncthreads();
    float inv = 1.0f / (red[0] + red[1] + red[2] + red[3]);
    int c = tid & 127, half = tid >> 7;
    float acc = 0.f;
    int k0 = half * 672;
    for (int k = k0; k < k0 + 672; ++k) acc += sc[k] * Vg[(b * NWIN + k) * 128 + c];
    part[tid] = acc;
    __syncthreads();
    if (tid < 128) {
        float y = (part[tid] + part[tid + 128]) * inv * ctr[row * 128 + tid];
        ycen[row * 128 + tid] = y;
    }
}

// K5: fused local window attention + gate + scatter into maps (d_out regions).
// One block per (window, batch). 256 thr = 64 tokens x 4 c'-chunks of 32.
__global__ __launch_bounds__(256) void k_local(
    const float* __restrict__ f0, const float* __restrict__ f1,
    const float* __restrict__ f2, const float* __restrict__ Mloc,
    const float* __restrict__ Wvl, const float* __restrict__ gw,
    const float* __restrict__ ycen, float* __restrict__ out) {
    int w = blockIdx.x, b = blockIdx.y;
    const float* f; int p0, HW, obase;
    window_src(w * WT, f0, f1, f2, f, p0, HW, obase);

    __shared__ __align__(16) float Xs[64 * 132];
    __shared__ float yg[128];
    __shared__ float g0[128];

    int tid = threadIdx.x;
    {   // stage window tokens: Xs[t][c], t = spatial lane (coalesced 256B reads)
        int lane = tid & 63, cg = tid >> 6;
        for (int c = cg; c < 128; c += 4)
            Xs[lane * 132 + c] = f[(b * 128 + c) * HW + p0 + lane];
        if (tid < 128) yg[tid] = ycen[(b * NWIN + w) * 128 + tid];
    }
    __syncthreads();

    int t = tid >> 2, qq = tid & 3;
    int c0 = qq * 32;

    // step B: XM[t][c0..c0+31] in registers (M = Wql Wkl^T)
    float4 xm[8];
    #pragma unroll
    for (int j = 0; j < 8; ++j) xm[j] = make_float4(0.f, 0.f, 0.f, 0.f);
    for (int c2 = 0; c2 < 128; ++c2) {
        float xv = Xs[t * 132 + c2];
        const float4* m4 = (const float4*)(Mloc + c2 * 128 + c0);
        #pragma unroll
        for (int j = 0; j < 8; ++j) fma4(xm[j], xv, m4[j]);
    }

    // step C: S[t][k] via quad partial-sums; softmax in registers.
    // thread keeps P[t][k] for k = 4i+qq.
    float p[16];
    {
        #pragma unroll
        for (int i = 0; i < 16; ++i) {
            float sv = 0.f;
            #pragma unroll
            for (int m = 0; m < 4; ++m) {
                int k = 4 * i + m;
                const float4* x4 = (const float4*)(Xs + k * 132 + c0);
                float s = 0.f;
                #pragma unroll
                for (int j = 0; j < 8; ++j) s += dot4(xm[j], x4[j]);
                s += __shfl_xor(s, 1);
                s += __shfl_xor(s, 2);
                if (m == qq) sv = s;
            }
            p[i] = sv * SCALE;
        }
        float rmax = -1e30f;
        #pragma unroll
        for (int i = 0; i < 16; ++i) rmax = fmaxf(rmax, p[i]);
        rmax = fmaxf(rmax, __shfl_xor(rmax, 1));
        rmax = fmaxf(rmax, __shfl_xor(rmax, 2));
        float lsum = 0.f;
        #pragma unroll
        for (int i = 0; i < 16; ++i) { p[i] = __expf(p[i] - rmax); lsum += p[i]; }
        lsum += __shfl_xor(lsum, 1);
        lsum += __shfl_xor(lsum, 2);
        float invs = 1.0f / lsum;
        #pragma unroll
        for (int i = 0; i < 16; ++i) p[i] *= invs;
    }

    // step D+E: PX = P @ X (quad-reduced 4 floats at a time), PXW += PX @ Wvl
    float4 aw[8];
    #pragma unroll
    for (int j = 0; j < 8; ++j) aw[j] = make_float4(0.f, 0.f, 0.f, 0.f);
    for (int c4 = 0; c4 < 32; ++c4) {
        float4 pp = make_float4(0.f, 0.f, 0.f, 0.f);
        #pragma unroll
        for (int i = 0; i < 16; ++i) {
            int k = 4 * i + qq;
            const float4* x4 = (const float4*)(Xs + k * 132);
            fma4(pp, p[i], x4[c4]);
        }
        pp.x += __shfl_xor(pp.x, 1); pp.x += __shfl_xor(pp.x, 2);
        pp.y += __shfl_xor(pp.y, 1); pp.y += __shfl_xor(pp.y, 2);
        pp.z += __shfl_xor(pp.z, 1); pp.z += __shfl_xor(pp.z, 2);
        pp.w += __shfl_xor(pp.w, 1); pp.w += __shfl_xor(pp.w, 2);
        const float4* w0 = (const float4*)(Wvl + (c4 * 4 + 0) * 128 + c0);
        const float4* w1 = (const float4*)(Wvl + (c4 * 4 + 1) * 128 + c0);
        const float4* w2 = (const float4*)(Wvl + (c4 * 4 + 2) * 128 + c0);
        const float4* w3 = (const float4*)(Wvl + (c4 * 4 + 3) * 128 + c0);
        #pragma unroll
        for (int j = 0; j < 8; ++j) {
            fma4(aw[j], pp.x, w0[j]);
            fma4(aw[j], pp.y, w1[j]);
            fma4(aw[j], pp.z, w2[j]);
            fma4(aw[j], pp.w, w3[j]);
        }
    }
    __syncthreads();  // everyone done READING Xs
    {   // y_local = PXW * X -> overwrite own Xs chunk
        float4* xrow = (float4*)(Xs + t * 132 + c0);
        #pragma unroll
        for (int j = 0; j < 8; ++j) {
            float4 xv = xrow[j];
            xv.x *= aw[j].x; xv.y *= aw[j].y; xv.z *= aw[j].z; xv.w *= aw[j].w;
            xrow[j] = xv;
        }
    }
    // g0 = y_global @ gate_w[:128]  (per-window row, done once)
    if (tid < 128) {
        float a = 0.f;
        for (int c2 = 0; c2 < 128; ++c2) a += yg[c2] * gw[c2 * 128 + tid];
        g0[tid] = a;
    }
    __syncthreads();

    // step F: alpha = sigmoid(g0 + y_l @ gate_w[128:]); y = a*yg + (1-a)*yl
    float4 ag[8];
    #pragma unroll
    for (int j = 0; j < 8; ++j) ag[j] = make_float4(0.f, 0.f, 0.f, 0.f);
    const float* G1 = gw + 128 * 128;
    for (int c2 = 0; c2 < 128; ++c2) {
        float xl = Xs[t * 132 + c2];
        const float4* g4 = (const float4*)(G1 + c2 * 128 + c0);
        #pragma unroll
        for (int j = 0; j < 8; ++j) fma4(ag[j], xl, g4[j]);
    }
    #pragma unroll
    for (int j = 0; j < 8; ++j) {
        int cb = c0 + j * 4;
        float av[4] = {ag[j].x, ag[j].y, ag[j].z, ag[j].w};
        #pragma unroll
        for (int cc = 0; cc < 4; ++cc) {
            int c = cb + cc;
            float a = 1.0f / (1.0f + __expf(-(av[cc] + g0[c])));
            float ylv = Xs[t * 132 + c];
            float y = a * yg[c] + (1.0f - a) * ylv;
            out[obase + (b * 128 + c) * HW + p0 + t] = y;
        }
    }
}

// K6/K7: conv3x3 (128->512) + PixelShuffle(2) + add-residual (in place on d_out).
// Block: 16x16 spatial tile, 32 out-channels; thread: 2x2 pos x 8 oc.
template <int H, int W>
__global__ __launch_bounds__(256) void k_conv_ps_add(
    const float* __restrict__ in, const float* __restrict__ wgt,
    float* __restrict__ out) {
    constexpr int TX = W / 16;
    int tileY = blockIdx.x / TX, tileX = blockIdx.x % TX;
    int ocBase = blockIdx.y * 32;
    int b = blockIdx.z;
    __shared__ __align__(16) float inT[16 * 324];  // [ic][18][18]
    __shared__ float wT[32 * 145];                 // [oc][16*9] pad->145
    int tid = threadIdx.x;
    int pg = tid & 63, og = tid >> 6;
    int pgy = pg >> 3, pgx = pg & 7;
    float acc[8][2][2] = {};
    int y0 = tileY * 16, x0 = tileX * 16;
    for (int icB = 0; icB < 128; icB += 16) {
        for (int idx = tid; idx < 16 * 324; idx += 256) {
            int ic = idx / 324, rem = idx - ic * 324;
            int r = rem / 18, cc = rem - r * 18;
            int gy = y0 + r - 1, gx = x0 + cc - 1;
            float v = 0.f;
            if (gy >= 0 && gy < H && gx >= 0 && gx < W)
                v = in[((b * 128 + icB + ic) * H + gy) * W + gx];
            inT[idx] = v;
        }
        for (int idx = tid; idx < 32 * 144; idx += 256) {
            int oc = idx / 144, rem = idx - oc * 144;
            wT[oc * 145 + rem] = wgt[(ocBase + oc) * 1152 + icB * 9 + rem];
        }
        __syncthreads();
        for (int ic = 0; ic < 16; ++ic) {
            float patch[4][4];
            #pragma unroll
            for (int i = 0; i < 4; ++i)
                #pragma unroll
                for (int j = 0; j < 4; ++j)
                    patch[i][j] = inT[ic * 324 + (pgy * 2 + i) * 18 + pgx * 2 + j];
            #pragma unroll
            for (int k = 0; k < 8; ++k) {
                const float* wp = &wT[(og * 8 + k) * 145 + ic * 9];
                float w0 = wp[0], w1 = wp[1], w2 = wp[2], w3 = wp[3], w4 = wp[4],
                      w5 = wp[5], w6 = wp[6], w7 = wp[7], w8 = wp[8];
                #pragma unroll
                for (int oy = 0; oy < 2; ++oy)
                    #pragma unroll
                    for (int ox = 0; ox < 2; ++ox)
                        acc[k][oy][ox] += w0 * patch[oy][ox] + w1 * patch[oy][ox + 1] +
                                          w2 * patch[oy][ox + 2] + w3 * patch[oy + 1][ox] +
                                          w4 * patch[oy + 1][ox + 1] + w5 * patch[oy + 1][ox + 2] +
                                          w6 * patch[oy + 2][ox] + w7 * patch[oy + 2][ox + 1] +
                                          w8 * patch[oy + 2][ox + 2];
            }
        }
        __syncthreads();
    }
    #pragma unroll
    for (int k = 0; k < 8; ++k) {
        int oc = ocBase + og * 8 + k;
        int c = oc >> 2, i2 = (oc >> 1) & 1, j2 = oc & 1;
        #pragma unroll
        for (int oy = 0; oy < 2; ++oy)
            #pragma unroll
            for (int ox = 0; ox < 2; ++ox) {
                int yy = y0 + pgy * 2 + oy, xx = x0 + pgx * 2 + ox;
                size_t oidx = ((size_t)(b * 128 + c) * (2 * H) + 2 * yy + i2) * (2 * W) +
                              2 * xx + j2;
                out[oidx] += acc[k][oy][ox];  // residual (maps[i]) written by k_local
            }
    }
}

extern "C" void kernel_launch(void* const* d_in, const int* in_sizes, int n_in,
                              void* d_out, int out_size, void* d_ws, size_t ws_size,
                              hipStream_t stream) {
    const float* f0 = (const float*)d_in[0];
    const float* f1 = (const float*)d_in[1];
    const float* f2 = (const float*)d_in[2];
    const float* Wq = (const float*)d_in[3];
    const float* Wk = (const float*)d_in[4];
    const float* Wv = (const float*)d_in[5];
    const float* Wql = (const float*)d_in[6];
    const float* Wkl = (const float*)d_in[7];
    const float* Wvl = (const float*)d_in[8];
    const float* gate_w = (const float*)d_in[9];
    const float* conv0 = (const float*)d_in[10];
    const float* conv1 = (const float*)d_in[11];
    float* out = (float*)d_out;
    float* ws = (float*)d_ws;

    float* Mloc = ws;                  // 16384
    float* Mglob = Mloc + 16384;       // 16384
    float* ctr = Mglob + 16384;        // 688128
    float* Tg = ctr + 688128;          // 688128
    float* Vg = Tg + 688128;           // 688128
    float* ycen = Vg + 688128;         // 688128

    k_mm<<<dim3(128, 2), 128, 0, stream>>>(Wql, Wkl, Wq, Wk, Mloc, Mglob);
    k_centers<<<dim3(NWIN, 4), 256, 0, stream>>>(f0, f1, f2, ctr);
    k_tgvg<<<dim3(NWIN, 4), 128, 0, stream>>>(ctr, Mglob, Wv, Tg, Vg);
    k_gattn<<<dim3(NWIN, 4), 256, 0, stream>>>(ctr, Tg, Vg, ycen);
    k_local<<<dim3(NWIN, 4), 256, 0, stream>>>(f0, f1, f2, Mloc, Wvl, gate_w, ycen, out);
    k_conv_ps_add<64, 64><<<dim3(16, 16, 4), 256, 0, stream>>>(out + OUT0, conv0, out + OUT1);
    k_conv_ps_add<128, 128><<<dim3(64, 16, 4), 256, 0, stream>>>(out + OUT1, conv1, out + OUT2);
}

// Round 2
// 2342.879 us; speedup vs baseline: 4.0100x; 4.0100x over previous
//
#include <hip/hip_runtime.h>
#include <math.h>

#define WT 64
#define NWIN 1344
constexpr float SCALE = 0.088388347648318447f;  // 128^-0.5

// out region offsets (floats)
#define OUT0 0
#define OUT1 2097152
#define OUT2 10485760

typedef __attribute__((ext_vector_type(8))) short bfrag;   // 8 bf16 (4 VGPRs)
typedef __attribute__((ext_vector_type(4))) float f32x4;   // MFMA C/D

#define MFMA16 __builtin_amdgcn_mfma_f32_16x16x32_bf16

__device__ __forceinline__ unsigned short f2b(float f) {
    union { float f; unsigned u; } v; v.f = f;
    unsigned r = v.u + 0x7fffu + ((v.u >> 16) & 1u);  // rne
    return (unsigned short)(r >> 16);
}
__device__ __forceinline__ float b2f(unsigned short u) {
    union { unsigned u; float f; } v; v.u = ((unsigned)u) << 16; return v.f;
}
__device__ __forceinline__ int pack2(float a, float b) {
    return (int)f2b(a) | ((int)f2b(b) << 16);
}

// swizzled LDS fragment loads: row-major bf16 tiles, byte ^= (row&7)<<4
__device__ __forceinline__ bfrag ld256(const char* region, int row, int k) {
    int off = (2 * k) ^ ((row & 7) << 4);
    return *(const bfrag*)(region + row * 256 + off);
}
__device__ __forceinline__ bfrag ld128(const char* region, int row, int k) {
    int off = (2 * k) ^ ((row & 7) << 4);
    return *(const bfrag*)(region + row * 128 + off);
}

__device__ __forceinline__ void fma4(float4& a, float s, const float4 b) {
    a.x += s * b.x; a.y += s * b.y; a.z += s * b.z; a.w += s * b.w;
}
__device__ __forceinline__ float dot4(const float4 a, const float4 b) {
    return a.x * b.x + a.y * b.y + a.z * b.z + a.w * b.w;
}

// K1: Mglob = Wq @ Wk^T (fp32, global path)
__global__ void k_mm(const float* __restrict__ Wq, const float* __restrict__ Wk,
                     float* __restrict__ Mglob) {
    int i = blockIdx.x, j = threadIdx.x;
    float acc = 0.f;
    for (int k = 0; k < 128; ++k) acc += Wq[i * 128 + k] * Wk[j * 128 + k];
    Mglob[i * 128 + j] = acc;
}

// K1b: bf16 transposed weight prep.
// MtB[n][k]   = (Wql @ Wkl^T)[k][n] = Wkl_row_n . Wql_row_k
// WvltB[n][k] = Wvl[k][n] ;  G1tB[n][k] = gate_w[128+k][n]
__global__ void k_prep(const float* __restrict__ Wql, const float* __restrict__ Wkl,
                       const float* __restrict__ Wvl, const float* __restrict__ gw,
                       unsigned short* __restrict__ MtB,
                       unsigned short* __restrict__ WvltB,
                       unsigned short* __restrict__ G1tB) {
    int n = blockIdx.x, k = threadIdx.x;
    if (blockIdx.y == 0) {
        float a = 0.f;
        for (int c = 0; c < 128; ++c) a += Wkl[n * 128 + c] * Wql[k * 128 + c];
        MtB[n * 128 + k] = f2b(a);
    } else if (blockIdx.y == 1) {
        WvltB[n * 128 + k] = f2b(Wvl[k * 128 + n]);
    } else {
        G1tB[n * 128 + k] = f2b(gw[(128 + k) * 128 + n]);
    }
}

__device__ __forceinline__ void window_src(int n0, const float* f0, const float* f1,
                                           const float* f2, const float*& f, int& p0,
                                           int& HW, int& obase) {
    if (n0 < 4096)        { f = f0; p0 = n0;          HW = 4096;  obase = OUT0; }
    else if (n0 < 20480)  { f = f1; p0 = n0 - 4096;   HW = 16384; obase = OUT1; }
    else                  { f = f2; p0 = n0 - 20480;  HW = 65536; obase = OUT2; }
}

// K2: window means -> centers [B,NWIN,128]
__global__ __launch_bounds__(256) void k_centers(
    const float* __restrict__ f0, const float* __restrict__ f1,
    const float* __restrict__ f2, float* __restrict__ ctr) {
    int w = blockIdx.x, b = blockIdx.y;
    const float* f; int p0, HW, ob;
    window_src(w * WT, f0, f1, f2, f, p0, HW, ob);
    int lane = threadIdx.x & 63, cg = threadIdx.x >> 6;
    for (int c = cg; c < 128; c += 4) {
        float v = f[(b * 128 + c) * HW + p0 + lane];
        #pragma unroll
        for (int off = 32; off; off >>= 1) v += __shfl_xor(v, off);
        if (lane == 0) ctr[(b * NWIN + w) * 128 + c] = v * (1.0f / 64.0f);
    }
}

// K3: Tg = centers @ Mglob ; Vg = centers @ Wv
__global__ __launch_bounds__(128) void k_tgvg(
    const float* __restrict__ ctr, const float* __restrict__ Mglob,
    const float* __restrict__ Wv, float* __restrict__ Tg, float* __restrict__ Vg) {
    int row = blockIdx.y * NWIN + blockIdx.x;
    int c = threadIdx.x;
    __shared__ __align__(16) float crow[128];
    crow[c] = ctr[row * 128 + c];
    __syncthreads();
    float a1 = 0.f, a2 = 0.f;
    for (int k = 0; k < 128; ++k) {
        float cv = crow[k];
        a1 += cv * Mglob[k * 128 + c];
        a2 += cv * Wv[k * 128 + c];
    }
    Tg[row * 128 + c] = a1;
    Vg[row * 128 + c] = a2;
}

// K4: global attention over 1344 window-centers; ycen = (attn @ Vg) * centers
__global__ __launch_bounds__(256) void k_gattn(
    const float* __restrict__ ctr, const float* __restrict__ Tg,
    const float* __restrict__ Vg, float* __restrict__ ycen) {
    int w = blockIdx.x, b = blockIdx.y;
    int row = b * NWIN + w;
    __shared__ __align__(16) float sc[NWIN];
    __shared__ __align__(16) float Trow[128];
    __shared__ float red[4];
    __shared__ float part[256];
    int tid = threadIdx.x;
    if (tid < 128) Trow[tid] = Tg[row * 128 + tid];
    __syncthreads();
    int quad = tid >> 2, qq = tid & 3;
    const float4* T4 = (const float4*)Trow;
    float lmax = -1e30f;
    for (int k = quad; k < NWIN; k += 64) {
        const float4* C4 = (const float4*)(ctr + (b * NWIN + k) * 128);
        float s = 0.f;
        #pragma unroll
        for (int j = 0; j < 8; ++j) s += dot4(T4[qq * 8 + j], C4[qq * 8 + j]);
        s += __shfl_xor(s, 1);
        s += __shfl_xor(s, 2);
        s *= SCALE;
        if (qq == 0) sc[k] = s;
        lmax = fmaxf(lmax, s);
    }
    #pragma unroll
    for (int off = 32; off; off >>= 1) lmax = fmaxf(lmax, __shfl_xor(lmax, off));
    if ((tid & 63) == 0) red[tid >> 6] = lmax;
    __syncthreads();
    float bmax = fmaxf(fmaxf(red[0], red[1]), fmaxf(red[2], red[3]));
    __syncthreads();
    float lsum = 0.f;
    for (int k = tid; k < NWIN; k += 256) {
        float e = __expf(sc[k] - bmax);
        sc[k] = e;
        lsum += e;
    }
    #pragma unroll
    for (int off = 32; off; off >>= 1) lsum += __shfl_xor(lsum, off);
    if ((tid & 63) == 0) red[tid >> 6] = lsum;
    __syncthreads();
    float inv = 1.0f / (red[0] + red[1] + red[2] + red[3]);
    int c = tid & 127, half = tid >> 7;
    float acc = 0.f;
    int k0 = half * 672;
    for (int k = k0; k < k0 + 672; ++k) acc += sc[k] * Vg[(b * NWIN + k) * 128 + c];
    part[tid] = acc;
    __syncthreads();
    if (tid < 128) {
        float y = (part[tid] + part[tid + 128]) * inv * ctr[row * 128 + tid];
        ycen[row * 128 + tid] = y;
    }
}

// ---------- K5: fused local window attention via MFMA ----------
// LDS region byte offsets (dynamic smem)
#define XB_OFF 0         // X bf16 [64 t][128 c], row 256B, swizzled
#define WT_OFF 16384     // weight bf16 [128 n][128 k], row 256B, swizzled
#define XM_OFF 49152     // XM bf16 [64 t][128 c] (later aliased by ylb)
#define PB_OFF 65536     // P bf16 [64 t][64 u], row 128B, swizzled
#define VT_OFF 73728     // V^T bf16 [128 c][64 u], row 128B, swizzled
#define YG_OFF 90112     // y_global row f32 [128]
#define G0_OFF 90624     // g0 row f32 [128]
#define SMEM_SZ 91136

__global__ __launch_bounds__(256, 1) void k_local_mfma(
    const float* __restrict__ f0, const float* __restrict__ f1,
    const float* __restrict__ f2,
    const unsigned short* __restrict__ MtB,
    const unsigned short* __restrict__ WvltB,
    const unsigned short* __restrict__ G1tB,
    const float* __restrict__ gw, const float* __restrict__ ycen,
    float* __restrict__ out) {
    extern __shared__ char smem[];
    char* Xb = smem + XB_OFF;
    char* Wt = smem + WT_OFF;
    char* XMb = smem + XM_OFF;   // also ylb in phase 4/5
    char* Pb = smem + PB_OFF;
    char* Vt = smem + VT_OFF;
    float* ygs = (float*)(smem + YG_OFF);
    float* g0s = (float*)(smem + G0_OFF);

    int w = blockIdx.x, b = blockIdx.y;
    const float* f; int p0, HW, obase;
    window_src(w * WT, f0, f1, f2, f, p0, HW, obase);

    int tid = threadIdx.x;
    int wid = tid >> 6, lane = tid & 63;
    int lr = lane & 15, lg = lane >> 4;

    // ---- phase 0: stage X (f32->bf16, swizzled) + Mt weights + yg/g0 ----
    {
        int t = tid & 63, cq = tid >> 6;
        const float* src = f + (size_t)(b * 128 + cq * 32) * HW + p0 + t;
        float xv[32];
        #pragma unroll
        for (int i = 0; i < 32; ++i) xv[i] = src[(size_t)i * HW];
        // Mt staging loads (8 x 16B per thread)
        int4 wreg[8];
        const int4* wsrc = (const int4*)MtB;
        #pragma unroll
        for (int j = 0; j < 8; ++j) wreg[j] = wsrc[j * 256 + tid];
        // g0 = yg @ G0 (threads 0..127); also stash yg row
        if (tid < 128) {
            const float* ygrow = ycen + ((size_t)b * NWIN + w) * 128;
            ygs[tid] = ygrow[tid];
            float a = 0.f;
            for (int c = 0; c < 128; ++c) a += ygrow[c] * gw[c * 128 + tid];
            g0s[tid] = a;
        }
        // write X tile
        #pragma unroll
        for (int j = 0; j < 4; ++j) {
            int c0 = cq * 32 + j * 8;
            int4 v;
            v.x = pack2(xv[j * 8 + 0], xv[j * 8 + 1]);
            v.y = pack2(xv[j * 8 + 2], xv[j * 8 + 3]);
            v.z = pack2(xv[j * 8 + 4], xv[j * 8 + 5]);
            v.w = pack2(xv[j * 8 + 6], xv[j * 8 + 7]);
            *(int4*)(Xb + t * 256 + ((2 * c0) ^ ((t & 7) << 4))) = v;
        }
        // write Mt tile
        #pragma unroll
        for (int j = 0; j < 8; ++j) {
            int ci = j * 256 + tid, n = ci >> 4, pos = ci & 15;
            *(int4*)(Wt + n * 256 + ((pos * 16) ^ ((n & 7) << 4))) = wreg[j];
        }
    }
    __syncthreads();  // B1

    int t = 16 * wid + lr;  // this lane's token (fixed through all phases)

    // ---- phase 1: XM^T = Mt(A) x X(B);  D: R=c, C=t -> pack to XMb[t][c] ----
    {
        f32x4 acc[8] = {};
        #pragma unroll
        for (int ks = 0; ks < 4; ++ks) {
            int k = ks * 32 + lg * 8;
            bfrag xb = ld256(Xb, t, k);
            #pragma unroll
            for (int ct = 0; ct < 8; ++ct) {
                bfrag am = ld256(Wt, 16 * ct + lr, k);
                acc[ct] = MFMA16(am, xb, acc[ct], 0, 0, 0);
            }
        }
        #pragma unroll
        for (int ct = 0; ct < 8; ++ct) {
            int c0 = 16 * ct + 4 * lg;
            int2 v; v.x = pack2(acc[ct][0], acc[ct][1]); v.y = pack2(acc[ct][2], acc[ct][3]);
            *(int2*)(XMb + t * 256 + ((2 * c0) ^ ((t & 7) << 4))) = v;
        }
    }
    __syncthreads();  // B2 (Wt(Mt) reads complete everywhere)

    // ---- phase 2: issue Wvlt loads; S^T = X(A) x XM(B); softmax; Pb ----
    {
        int4 wreg[8];
        const int4* wsrc = (const int4*)WvltB;
        #pragma unroll
        for (int j = 0; j < 8; ++j) wreg[j] = wsrc[j * 256 + tid];

        f32x4 s[4] = {};
        #pragma unroll
        for (int ks = 0; ks < 4; ++ks) {
            int k = ks * 32 + lg * 8;
            bfrag bxm = ld256(XMb, t, k);
            #pragma unroll
            for (int ut = 0; ut < 4; ++ut) {
                bfrag ax = ld256(Xb, 16 * ut + lr, k);
                s[ut] = MFMA16(ax, bxm, s[ut], 0, 0, 0);
            }
        }
        // softmax over u (R dim): lane holds 16 of 64, reduce across lg via xor 16,32
        float m = -1e30f;
        #pragma unroll
        for (int ut = 0; ut < 4; ++ut)
            #pragma unroll
            for (int r = 0; r < 4; ++r) m = fmaxf(m, s[ut][r]);
        m = fmaxf(m, __shfl_xor(m, 16));
        m = fmaxf(m, __shfl_xor(m, 32));
        float sum = 0.f;
        float e[4][4];
        #pragma unroll
        for (int ut = 0; ut < 4; ++ut)
            #pragma unroll
            for (int r = 0; r < 4; ++r) {
                e[ut][r] = __expf((s[ut][r] - m) * SCALE);
                sum += e[ut][r];
            }
        sum += __shfl_xor(sum, 16);
        sum += __shfl_xor(sum, 32);
        float pinv = 1.0f / sum;
        #pragma unroll
        for (int ut = 0; ut < 4; ++ut) {
            int u0 = 16 * ut + 4 * lg;
            int2 v;
            v.x = pack2(e[ut][0] * pinv, e[ut][1] * pinv);
            v.y = pack2(e[ut][2] * pinv, e[ut][3] * pinv);
            *(int2*)(Pb + t * 128 + ((2 * u0) ^ ((t & 7) << 4))) = v;
        }
        // stage Wvlt into Wt (loads already in flight)
        #pragma unroll
        for (int j = 0; j < 8; ++j) {
            int ci = j * 256 + tid, n = ci >> 4, pos = ci & 15;
            *(int4*)(Wt + n * 256 + ((pos * 16) ^ ((n & 7) << 4))) = wreg[j];
        }
    }
    __syncthreads();  // B3

    // ---- phase 3: V = X(A) x Wvlt(B); D: R=u, C=c -> pack to Vt[c][u] ----
    {
        f32x4 vacc[8] = {};
        #pragma unroll
        for (int ks = 0; ks < 4; ++ks) {
            int k = ks * 32 + lg * 8;
            bfrag ax = ld256(Xb, t, k);
            #pragma unroll
            for (int ct = 0; ct < 8; ++ct) {
                bfrag bw = ld256(Wt, 16 * ct + lr, k);
                vacc[ct] = MFMA16(ax, bw, vacc[ct], 0, 0, 0);
            }
        }
        #pragma unroll
        for (int ct = 0; ct < 8; ++ct) {
            int c = 16 * ct + lr;
            int u0 = 16 * wid + 4 * lg;
            int2 v; v.x = pack2(vacc[ct][0], vacc[ct][1]); v.y = pack2(vacc[ct][2], vacc[ct][3]);
            *(int2*)(Vt + c * 128 + ((2 * u0) ^ ((c & 7) << 4))) = v;
        }
    }
    __syncthreads();  // B4 (Vt complete; Wt(Wvlt) reads complete)

    // ---- phase 4: issue G1t loads; Y^T = Vt(A) x P(B); yl = Y*X -> ylb ----
    float yl[8][4];
    {
        int4 wreg[8];
        const int4* wsrc = (const int4*)G1tB;
        #pragma unroll
        for (int j = 0; j < 8; ++j) wreg[j] = wsrc[j * 256 + tid];

        f32x4 y[8] = {};
        #pragma unroll
        for (int us = 0; us < 2; ++us) {
            int u = us * 32 + lg * 8;
            bfrag bp = ld128(Pb, t, u);
            #pragma unroll
            for (int ct = 0; ct < 8; ++ct) {
                bfrag av = ld128(Vt, 16 * ct + lr, u);
                y[ct] = MFMA16(av, bp, y[ct], 0, 0, 0);
            }
        }
        char* ylb = XMb;  // XM dead after phase 2
        #pragma unroll
        for (int ct = 0; ct < 8; ++ct) {
            int c0 = 16 * ct + 4 * lg;
            int2 xw = *(const int2*)(Xb + t * 256 + ((2 * c0) ^ ((t & 7) << 4)));
            float x0 = b2f((unsigned short)(xw.x & 0xffff));
            float x1 = b2f((unsigned short)((unsigned)xw.x >> 16));
            float x2 = b2f((unsigned short)(xw.y & 0xffff));
            float x3 = b2f((unsigned short)((unsigned)xw.y >> 16));
            yl[ct][0] = y[ct][0] * x0;
            yl[ct][1] = y[ct][1] * x1;
            yl[ct][2] = y[ct][2] * x2;
            yl[ct][3] = y[ct][3] * x3;
            int2 v; v.x = pack2(yl[ct][0], yl[ct][1]); v.y = pack2(yl[ct][2], yl[ct][3]);
            *(int2*)(ylb + t * 256 + ((2 * c0) ^ ((t & 7) << 4))) = v;
        }
        // stage G1t into Wt
        #pragma unroll
        for (int j = 0; j < 8; ++j) {
            int ci = j * 256 + tid, n = ci >> 4, pos = ci & 15;
            *(int4*)(Wt + n * 256 + ((pos * 16) ^ ((n & 7) << 4))) = wreg[j];
        }
    }
    __syncthreads();  // B5

    // ---- phase 5: G^T = G1t(A) x yl(B); alpha; final blend + store ----
    {
        const char* ylb = XMb;
        f32x4 g[8] = {};
        #pragma unroll
        for (int ks = 0; ks < 4; ++ks) {
            int k = ks * 32 + lg * 8;
            bfrag byl = ld256(ylb, t, k);
            #pragma unroll
            for (int nt = 0; nt < 8; ++nt) {
                bfrag ag = ld256(Wt, 16 * nt + lr, k);
                g[nt] = MFMA16(ag, byl, g[nt], 0, 0, 0);
            }
        }
        #pragma unroll
        for (int nt = 0; nt < 8; ++nt) {
            #pragma unroll
            for (int r = 0; r < 4; ++r) {
                int c = 16 * nt + 4 * lg + r;
                float a = 1.0f / (1.0f + __expf(-(g[nt][r] + g0s[c])));
                float yv = a * ygs[c] + (1.0f - a) * yl[nt][r];
                out[obase + (size_t)(b * 128 + c) * HW + p0 + t] = yv;
            }
        }
    }
}

// K6/K7: conv3x3 (128->512) + PixelShuffle(2) + add-residual (in place on d_out).
template <int H, int W>
__global__ __launch_bounds__(256) void k_conv_ps_add(
    const float* __restrict__ in, const float* __restrict__ wgt,
    float* __restrict__ out) {
    constexpr int TX = W / 16;
    int tileY = blockIdx.x / TX, tileX = blockIdx.x % TX;
    int ocBase = blockIdx.y * 32;
    int b = blockIdx.z;
    __shared__ __align__(16) float inT[16 * 324];  // [ic][18][18]
    __shared__ float wT[32 * 145];                 // [oc][16*9] pad->145
    int tid = threadIdx.x;
    int pg = tid & 63, og = tid >> 6;
    int pgy = pg >> 3, pgx = pg & 7;
    float acc[8][2][2] = {};
    int y0 = tileY * 16, x0 = tileX * 16;
    for (int icB = 0; icB < 128; icB += 16) {
        for (int idx = tid; idx < 16 * 324; idx += 256) {
            int ic = idx / 324, rem = idx - ic * 324;
            int r = rem / 18, cc = rem - r * 18;
            int gy = y0 + r - 1, gx = x0 + cc - 1;
            float v = 0.f;
            if (gy >= 0 && gy < H && gx >= 0 && gx < W)
                v = in[((b * 128 + icB + ic) * H + gy) * W + gx];
            inT[idx] = v;
        }
        for (int idx = tid; idx < 32 * 144; idx += 256) {
            int oc = idx / 144, rem = idx - oc * 144;
            wT[oc * 145 + rem] = wgt[(ocBase + oc) * 1152 + icB * 9 + rem];
        }
        __syncthreads();
        for (int ic = 0; ic < 16; ++ic) {
            float patch[4][4];
            #pragma unroll
            for (int i = 0; i < 4; ++i)
                #pragma unroll
                for (int j = 0; j < 4; ++j)
                    patch[i][j] = inT[ic * 324 + (pgy * 2 + i) * 18 + pgx * 2 + j];
            #pragma unroll
            for (int k = 0; k < 8; ++k) {
                const float* wp = &wT[(og * 8 + k) * 145 + ic * 9];
                float w0 = wp[0], w1 = wp[1], w2 = wp[2], w3 = wp[3], w4 = wp[4],
                      w5 = wp[5], w6 = wp[6], w7 = wp[7], w8 = wp[8];
                #pragma unroll
                for (int oy = 0; oy < 2; ++oy)
                    #pragma unroll
                    for (int ox = 0; ox < 2; ++ox)
                        acc[k][oy][ox] += w0 * patch[oy][ox] + w1 * patch[oy][ox + 1] +
                                          w2 * patch[oy][ox + 2] + w3 * patch[oy + 1][ox] +
                                          w4 * patch[oy + 1][ox + 1] + w5 * patch[oy + 1][ox + 2] +
                                          w6 * patch[oy + 2][ox] + w7 * patch[oy + 2][ox + 1] +
                                          w8 * patch[oy + 2][ox + 2];
            }
        }
        __syncthreads();
    }
    #pragma unroll
    for (int k = 0; k < 8; ++k) {
        int oc = ocBase + og * 8 + k;
        int c = oc >> 2, i2 = (oc >> 1) & 1, j2 = oc & 1;
        #pragma unroll
        for (int oy = 0; oy < 2; ++oy)
            #pragma unroll
            for (int ox = 0; ox < 2; ++ox) {
                int yy = y0 + pgy * 2 + oy, xx = x0 + pgx * 2 + ox;
                size_t oidx = ((size_t)(b * 128 + c) * (2 * H) + 2 * yy + i2) * (2 * W) +
                              2 * xx + j2;
                out[oidx] += acc[k][oy][ox];
            }
    }
}

extern "C" void kernel_launch(void* const* d_in, const int* in_sizes, int n_in,
                              void* d_out, int out_size, void* d_ws, size_t ws_size,
                              hipStream_t stream) {
    const float* f0 = (const float*)d_in[0];
    const float* f1 = (const float*)d_in[1];
    const float* f2 = (const float*)d_in[2];
    const float* Wq = (const float*)d_in[3];
    const float* Wk = (const float*)d_in[4];
    const float* Wv = (const float*)d_in[5];
    const float* Wql = (const float*)d_in[6];
    const float* Wkl = (const float*)d_in[7];
    const float* Wvl = (const float*)d_in[8];
    const float* gate_w = (const float*)d_in[9];
    const float* conv0 = (const float*)d_in[10];
    const float* conv1 = (const float*)d_in[11];
    float* out = (float*)d_out;
    float* ws = (float*)d_ws;

    float* Mglob = ws;                    // 16384
    float* ctr = Mglob + 16384;           // 688128
    float* Tg = ctr + 688128;             // 688128
    float* Vg = Tg + 688128;              // 688128
    float* ycen = Vg + 688128;            // 688128
    unsigned short* MtB = (unsigned short*)(ycen + 688128);  // 16384 bf16
    unsigned short* WvltB = MtB + 16384;                     // 16384 bf16
    unsigned short* G1tB = WvltB + 16384;                    // 16384 bf16

    hipFuncSetAttribute((const void*)k_local_mfma,
                        hipFuncAttributeMaxDynamicSharedMemorySize, SMEM_SZ);

    k_mm<<<dim3(128), 128, 0, stream>>>(Wq, Wk, Mglob);
    k_prep<<<dim3(128, 3), 128, 0, stream>>>(Wql, Wkl, Wvl, gate_w, MtB, WvltB, G1tB);
    k_centers<<<dim3(NWIN, 4), 256, 0, stream>>>(f0, f1, f2, ctr);
    k_tgvg<<<dim3(NWIN, 4), 128, 0, stream>>>(ctr, Mglob, Wv, Tg, Vg);
    k_gattn<<<dim3(NWIN, 4), 256, 0, stream>>>(ctr, Tg, Vg, ycen);
    k_local_mfma<<<dim3(NWIN, 4), 256, SMEM_SZ, stream>>>(
        f0, f1, f2, MtB, WvltB, G1tB, gate_w, ycen, out);
    k_conv_ps_add<64, 64><<<dim3(16, 16, 4), 256, 0, stream>>>(out + OUT0, conv0, out + OUT1);
    k_conv_ps_add<128, 128><<<dim3(64, 16, 4), 256, 0, stream>>>(out + OUT1, conv1, out + OUT2);
}

// Round 3
// 1182.103 us; speedup vs baseline: 7.9477x; 1.9820x over previous
//
#include <hip/hip_runtime.h>
#include <math.h>

#define WT 64
#define NWIN 1344
constexpr float SCALE = 0.088388347648318447f;  // 128^-0.5

// out region offsets (floats)
#define OUT0 0
#define OUT1 2097152
#define OUT2 10485760

typedef __attribute__((ext_vector_type(8))) short bfrag;      // 8 bf16
typedef __attribute__((ext_vector_type(8))) _Float16 hfrag;   // 8 fp16
typedef __attribute__((ext_vector_type(4))) float f32x4;      // MFMA C/D

#define MFMA16 __builtin_amdgcn_mfma_f32_16x16x32_bf16
#define MFMA16H __builtin_amdgcn_mfma_f32_16x16x32_f16

__device__ __forceinline__ unsigned short f2b(float f) {
    union { float f; unsigned u; } v; v.f = f;
    unsigned r = v.u + 0x7fffu + ((v.u >> 16) & 1u);  // rne
    return (unsigned short)(r >> 16);
}
__device__ __forceinline__ float b2f(unsigned short u) {
    union { unsigned u; float f; } v; v.u = ((unsigned)u) << 16; return v.f;
}
__device__ __forceinline__ int pack2(float a, float b) {
    return (int)f2b(a) | ((int)f2b(b) << 16);
}

// swizzled LDS fragment loads: row-major bf16 tiles, byte ^= (row&7)<<4
__device__ __forceinline__ bfrag ld256(const char* region, int row, int k) {
    int off = (2 * k) ^ ((row & 7) << 4);
    return *(const bfrag*)(region + row * 256 + off);
}
__device__ __forceinline__ bfrag ld128(const char* region, int row, int k) {
    int off = (2 * k) ^ ((row & 7) << 4);
    return *(const bfrag*)(region + row * 128 + off);
}

__device__ __forceinline__ void fma4(float4& a, float s, const float4 b) {
    a.x += s * b.x; a.y += s * b.y; a.z += s * b.z; a.w += s * b.w;
}
__device__ __forceinline__ float dot4(const float4 a, const float4 b) {
    return a.x * b.x + a.y * b.y + a.z * b.z + a.w * b.w;
}

// K1: Mglob = Wq @ Wk^T (fp32, global path)
__global__ void k_mm(const float* __restrict__ Wq, const float* __restrict__ Wk,
                     float* __restrict__ Mglob) {
    int i = blockIdx.x, j = threadIdx.x;
    float acc = 0.f;
    for (int k = 0; k < 128; ++k) acc += Wq[i * 128 + k] * Wk[j * 128 + k];
    Mglob[i * 128 + j] = acc;
}

// K1b: bf16 transposed weight prep for local path.
__global__ void k_prep(const float* __restrict__ Wql, const float* __restrict__ Wkl,
                       const float* __restrict__ Wvl, const float* __restrict__ gw,
                       unsigned short* __restrict__ MtB,
                       unsigned short* __restrict__ WvltB,
                       unsigned short* __restrict__ G1tB) {
    int n = blockIdx.x, k = threadIdx.x;
    if (blockIdx.y == 0) {
        float a = 0.f;
        for (int c = 0; c < 128; ++c) a += Wkl[n * 128 + c] * Wql[k * 128 + c];
        MtB[n * 128 + k] = f2b(a);
    } else if (blockIdx.y == 1) {
        WvltB[n * 128 + k] = f2b(Wvl[k * 128 + n]);
    } else {
        G1tB[n * 128 + k] = f2b(gw[(128 + k) * 128 + n]);
    }
}

// K1c: conv weight prep -> fp16 "LDS image" layout [36][512][32]
// slice = ics*9 + tap; element (oc, s*8+e) = w[oc][ics*32 + (s^(oc&3))*8+e][tap]
__global__ __launch_bounds__(256) void k_prep_conv(
    const float* __restrict__ w0, const float* __restrict__ w1,
    _Float16* __restrict__ W0, _Float16* __restrict__ W1) {
    int idx = blockIdx.x * 256 + threadIdx.x;  // < 589824 = 36*512*32
    const float* w = blockIdx.y ? w1 : w0;
    _Float16* o = blockIdx.y ? W1 : W0;
    int t = idx & 31, oc = (idx >> 5) & 511, slice = idx >> 14;
    int ics = slice / 9, tap = slice % 9;
    int s = t >> 3, e = t & 7;
    int ic = ics * 32 + ((s ^ (oc & 3)) * 8 + e);
    o[idx] = (_Float16)w[((size_t)oc * 128 + ic) * 9 + tap];
}

__device__ __forceinline__ void window_src(int n0, const float* f0, const float* f1,
                                           const float* f2, const float*& f, int& p0,
                                           int& HW, int& obase) {
    if (n0 < 4096)        { f = f0; p0 = n0;          HW = 4096;  obase = OUT0; }
    else if (n0 < 20480)  { f = f1; p0 = n0 - 4096;   HW = 16384; obase = OUT1; }
    else                  { f = f2; p0 = n0 - 20480;  HW = 65536; obase = OUT2; }
}

// K2: window means -> centers [B,NWIN,128]
__global__ __launch_bounds__(256) void k_centers(
    const float* __restrict__ f0, const float* __restrict__ f1,
    const float* __restrict__ f2, float* __restrict__ ctr) {
    int w = blockIdx.x, b = blockIdx.y;
    const float* f; int p0, HW, ob;
    window_src(w * WT, f0, f1, f2, f, p0, HW, ob);
    int lane = threadIdx.x & 63, cg = threadIdx.x >> 6;
    for (int c = cg; c < 128; c += 4) {
        float v = f[(b * 128 + c) * HW + p0 + lane];
        #pragma unroll
        for (int off = 32; off; off >>= 1) v += __shfl_xor(v, off);
        if (lane == 0) ctr[(b * NWIN + w) * 128 + c] = v * (1.0f / 64.0f);
    }
}

// K3: Tg = centers @ Mglob ; Vg = centers @ Wv
__global__ __launch_bounds__(128) void k_tgvg(
    const float* __restrict__ ctr, const float* __restrict__ Mglob,
    const float* __restrict__ Wv, float* __restrict__ Tg, float* __restrict__ Vg) {
    int row = blockIdx.y * NWIN + blockIdx.x;
    int c = threadIdx.x;
    __shared__ __align__(16) float crow[128];
    crow[c] = ctr[row * 128 + c];
    __syncthreads();
    float a1 = 0.f, a2 = 0.f;
    for (int k = 0; k < 128; ++k) {
        float cv = crow[k];
        a1 += cv * Mglob[k * 128 + c];
        a2 += cv * Wv[k * 128 + c];
    }
    Tg[row * 128 + c] = a1;
    Vg[row * 128 + c] = a2;
}

// K4: global attention over 1344 window-centers
__global__ __launch_bounds__(256) void k_gattn(
    const float* __restrict__ ctr, const float* __restrict__ Tg,
    const float* __restrict__ Vg, float* __restrict__ ycen) {
    int w = blockIdx.x, b = blockIdx.y;
    int row = b * NWIN + w;
    __shared__ __align__(16) float sc[NWIN];
    __shared__ __align__(16) float Trow[128];
    __shared__ float red[4];
    __shared__ float part[256];
    int tid = threadIdx.x;
    if (tid < 128) Trow[tid] = Tg[row * 128 + tid];
    __syncthreads();
    int quad = tid >> 2, qq = tid & 3;
    const float4* T4 = (const float4*)Trow;
    float lmax = -1e30f;
    for (int k = quad; k < NWIN; k += 64) {
        const float4* C4 = (const float4*)(ctr + (b * NWIN + k) * 128);
        float s = 0.f;
        #pragma unroll
        for (int j = 0; j < 8; ++j) s += dot4(T4[qq * 8 + j], C4[qq * 8 + j]);
        s += __shfl_xor(s, 1);
        s += __shfl_xor(s, 2);
        s *= SCALE;
        if (qq == 0) sc[k] = s;
        lmax = fmaxf(lmax, s);
    }
    #pragma unroll
    for (int off = 32; off; off >>= 1) lmax = fmaxf(lmax, __shfl_xor(lmax, off));
    if ((tid & 63) == 0) red[tid >> 6] = lmax;
    __syncthreads();
    float bmax = fmaxf(fmaxf(red[0], red[1]), fmaxf(red[2], red[3]));
    __syncthreads();
    float lsum = 0.f;
    for (int k = tid; k < NWIN; k += 256) {
        float e = __expf(sc[k] - bmax);
        sc[k] = e;
        lsum += e;
    }
    #pragma unroll
    for (int off = 32; off; off >>= 1) lsum += __shfl_xor(lsum, off);
    if ((tid & 63) == 0) red[tid >> 6] = lsum;
    __syncthreads();
    float inv = 1.0f / (red[0] + red[1] + red[2] + red[3]);
    int c = tid & 127, half = tid >> 7;
    float acc = 0.f;
    int k0 = half * 672;
    for (int k = k0; k < k0 + 672; ++k) acc += sc[k] * Vg[(b * NWIN + k) * 128 + c];
    part[tid] = acc;
    __syncthreads();
    if (tid < 128) {
        float y = (part[tid] + part[tid + 128]) * inv * ctr[row * 128 + tid];
        ycen[row * 128 + tid] = y;
    }
}

// ---------- K5: fused local window attention via MFMA ----------
#define XB_OFF 0
#define WT_OFF 16384
#define XM_OFF 49152
#define PB_OFF 65536
#define VT_OFF 73728
#define YG_OFF 90112
#define G0_OFF 90624
#define SMEM_SZ 91136

__global__ __launch_bounds__(256, 1) void k_local_mfma(
    const float* __restrict__ f0, const float* __restrict__ f1,
    const float* __restrict__ f2,
    const unsigned short* __restrict__ MtB,
    const unsigned short* __restrict__ WvltB,
    const unsigned short* __restrict__ G1tB,
    const float* __restrict__ gw, const float* __restrict__ ycen,
    float* __restrict__ out) {
    extern __shared__ char smem[];
    char* Xb = smem + XB_OFF;
    char* Wt = smem + WT_OFF;
    char* XMb = smem + XM_OFF;
    char* Pb = smem + PB_OFF;
    char* Vt = smem + VT_OFF;
    float* ygs = (float*)(smem + YG_OFF);
    float* g0s = (float*)(smem + G0_OFF);

    int w = blockIdx.x, b = blockIdx.y;
    const float* f; int p0, HW, obase;
    window_src(w * WT, f0, f1, f2, f, p0, HW, obase);

    int tid = threadIdx.x;
    int wid = tid >> 6, lane = tid & 63;
    int lr = lane & 15, lg = lane >> 4;

    {
        int t = tid & 63, cq = tid >> 6;
        const float* src = f + (size_t)(b * 128 + cq * 32) * HW + p0 + t;
        float xv[32];
        #pragma unroll
        for (int i = 0; i < 32; ++i) xv[i] = src[(size_t)i * HW];
        int4 wreg[8];
        const int4* wsrc = (const int4*)MtB;
        #pragma unroll
        for (int j = 0; j < 8; ++j) wreg[j] = wsrc[j * 256 + tid];
        if (tid < 128) {
            const float* ygrow = ycen + ((size_t)b * NWIN + w) * 128;
            ygs[tid] = ygrow[tid];
            float a = 0.f;
            for (int c = 0; c < 128; ++c) a += ygrow[c] * gw[c * 128 + tid];
            g0s[tid] = a;
        }
        #pragma unroll
        for (int j = 0; j < 4; ++j) {
            int c0 = cq * 32 + j * 8;
            int4 v;
            v.x = pack2(xv[j * 8 + 0], xv[j * 8 + 1]);
            v.y = pack2(xv[j * 8 + 2], xv[j * 8 + 3]);
            v.z = pack2(xv[j * 8 + 4], xv[j * 8 + 5]);
            v.w = pack2(xv[j * 8 + 6], xv[j * 8 + 7]);
            *(int4*)(Xb + t * 256 + ((2 * c0) ^ ((t & 7) << 4))) = v;
        }
        #pragma unroll
        for (int j = 0; j < 8; ++j) {
            int ci = j * 256 + tid, n = ci >> 4, pos = ci & 15;
            *(int4*)(Wt + n * 256 + ((pos * 16) ^ ((n & 7) << 4))) = wreg[j];
        }
    }
    __syncthreads();

    int t = 16 * wid + lr;

    {   // phase 1: XM^T
        f32x4 acc[8] = {};
        #pragma unroll
        for (int ks = 0; ks < 4; ++ks) {
            int k = ks * 32 + lg * 8;
            bfrag xb = ld256(Xb, t, k);
            #pragma unroll
            for (int ct = 0; ct < 8; ++ct) {
                bfrag am = ld256(Wt, 16 * ct + lr, k);
                acc[ct] = MFMA16(am, xb, acc[ct], 0, 0, 0);
            }
        }
        #pragma unroll
        for (int ct = 0; ct < 8; ++ct) {
            int c0 = 16 * ct + 4 * lg;
            int2 v; v.x = pack2(acc[ct][0], acc[ct][1]); v.y = pack2(acc[ct][2], acc[ct][3]);
            *(int2*)(XMb + t * 256 + ((2 * c0) ^ ((t & 7) << 4))) = v;
        }
    }
    __syncthreads();

    {   // phase 2: S^T + softmax
        int4 wreg[8];
        const int4* wsrc = (const int4*)WvltB;
        #pragma unroll
        for (int j = 0; j < 8; ++j) wreg[j] = wsrc[j * 256 + tid];

        f32x4 s[4] = {};
        #pragma unroll
        for (int ks = 0; ks < 4; ++ks) {
            int k = ks * 32 + lg * 8;
            bfrag bxm = ld256(XMb, t, k);
            #pragma unroll
            for (int ut = 0; ut < 4; ++ut) {
                bfrag ax = ld256(Xb, 16 * ut + lr, k);
                s[ut] = MFMA16(ax, bxm, s[ut], 0, 0, 0);
            }
        }
        float m = -1e30f;
        #pragma unroll
        for (int ut = 0; ut < 4; ++ut)
            #pragma unroll
            for (int r = 0; r < 4; ++r) m = fmaxf(m, s[ut][r]);
        m = fmaxf(m, __shfl_xor(m, 16));
        m = fmaxf(m, __shfl_xor(m, 32));
        float sum = 0.f;
        float e[4][4];
        #pragma unroll
        for (int ut = 0; ut < 4; ++ut)
            #pragma unroll
            for (int r = 0; r < 4; ++r) {
                e[ut][r] = __expf((s[ut][r] - m) * SCALE);
                sum += e[ut][r];
            }
        sum += __shfl_xor(sum, 16);
        sum += __shfl_xor(sum, 32);
        float pinv = 1.0f / sum;
        #pragma unroll
        for (int ut = 0; ut < 4; ++ut) {
            int u0 = 16 * ut + 4 * lg;
            int2 v;
            v.x = pack2(e[ut][0] * pinv, e[ut][1] * pinv);
            v.y = pack2(e[ut][2] * pinv, e[ut][3] * pinv);
            *(int2*)(Pb + t * 128 + ((2 * u0) ^ ((t & 7) << 4))) = v;
        }
        #pragma unroll
        for (int j = 0; j < 8; ++j) {
            int ci = j * 256 + tid, n = ci >> 4, pos = ci & 15;
            *(int4*)(Wt + n * 256 + ((pos * 16) ^ ((n & 7) << 4))) = wreg[j];
        }
    }
    __syncthreads();

    {   // phase 3: V^T
        f32x4 vacc[8] = {};
        #pragma unroll
        for (int ks = 0; ks < 4; ++ks) {
            int k = ks * 32 + lg * 8;
            bfrag ax = ld256(Xb, t, k);
            #pragma unroll
            for (int ct = 0; ct < 8; ++ct) {
                bfrag bw = ld256(Wt, 16 * ct + lr, k);
                vacc[ct] = MFMA16(ax, bw, vacc[ct], 0, 0, 0);
            }
        }
        #pragma unroll
        for (int ct = 0; ct < 8; ++ct) {
            int c = 16 * ct + lr;
            int u0 = 16 * wid + 4 * lg;
            int2 v; v.x = pack2(vacc[ct][0], vacc[ct][1]); v.y = pack2(vacc[ct][2], vacc[ct][3]);
            *(int2*)(Vt + c * 128 + ((2 * u0) ^ ((c & 7) << 4))) = v;
        }
    }
    __syncthreads();

    float yl[8][4];
    {   // phase 4: Y^T = Vt x P ; yl = Y*X
        int4 wreg[8];
        const int4* wsrc = (const int4*)G1tB;
        #pragma unroll
        for (int j = 0; j < 8; ++j) wreg[j] = wsrc[j * 256 + tid];

        f32x4 y[8] = {};
        #pragma unroll
        for (int us = 0; us < 2; ++us) {
            int u = us * 32 + lg * 8;
            bfrag bp = ld128(Pb, t, u);
            #pragma unroll
            for (int ct = 0; ct < 8; ++ct) {
                bfrag av = ld128(Vt, 16 * ct + lr, u);
                y[ct] = MFMA16(av, bp, y[ct], 0, 0, 0);
            }
        }
        char* ylb = XMb;
        #pragma unroll
        for (int ct = 0; ct < 8; ++ct) {
            int c0 = 16 * ct + 4 * lg;
            int2 xw = *(const int2*)(Xb + t * 256 + ((2 * c0) ^ ((t & 7) << 4)));
            float x0 = b2f((unsigned short)(xw.x & 0xffff));
            float x1 = b2f((unsigned short)((unsigned)xw.x >> 16));
            float x2 = b2f((unsigned short)(xw.y & 0xffff));
            float x3 = b2f((unsigned short)((unsigned)xw.y >> 16));
            yl[ct][0] = y[ct][0] * x0;
            yl[ct][1] = y[ct][1] * x1;
            yl[ct][2] = y[ct][2] * x2;
            yl[ct][3] = y[ct][3] * x3;
            int2 v; v.x = pack2(yl[ct][0], yl[ct][1]); v.y = pack2(yl[ct][2], yl[ct][3]);
            *(int2*)(ylb + t * 256 + ((2 * c0) ^ ((t & 7) << 4))) = v;
        }
        #pragma unroll
        for (int j = 0; j < 8; ++j) {
            int ci = j * 256 + tid, n = ci >> 4, pos = ci & 15;
            *(int4*)(Wt + n * 256 + ((pos * 16) ^ ((n & 7) << 4))) = wreg[j];
        }
    }
    __syncthreads();

    {   // phase 5: gate + blend + store
        const char* ylb = XMb;
        f32x4 g[8] = {};
        #pragma unroll
        for (int ks = 0; ks < 4; ++ks) {
            int k = ks * 32 + lg * 8;
            bfrag byl = ld256(ylb, t, k);
            #pragma unroll
            for (int nt = 0; nt < 8; ++nt) {
                bfrag ag = ld256(Wt, 16 * nt + lr, k);
                g[nt] = MFMA16(ag, byl, g[nt], 0, 0, 0);
            }
        }
        #pragma unroll
        for (int nt = 0; nt < 8; ++nt) {
            #pragma unroll
            for (int r = 0; r < 4; ++r) {
                int c = 16 * nt + 4 * lg + r;
                float a = 1.0f / (1.0f + __expf(-(g[nt][r] + g0s[c])));
                float yv = a * ygs[c] + (1.0f - a) * yl[nt][r];
                out[obase + (size_t)(b * 128 + c) * HW + p0 + t] = yv;
            }
        }
    }
}

// ---------- K6/K7: conv3x3(128->512) + PixelShuffle + residual, MFMA fp16 ----
// Block: M=128 pixels (8 rows x 16 cols), N=256 oc, 4 waves (each 4 n-tiles).
// K = 4 ic-slices x 9 taps x 32. Taps = row-shifted reads of staged input slice.
template <int H, int W>
__global__ __launch_bounds__(256, 2) void k_conv_mfma(
    const float* __restrict__ in, const _Float16* __restrict__ Wcv,
    float* __restrict__ out) {
    constexpr int TXN = W / 16;
    int tile = blockIdx.x;
    int ty = tile / TXN, tx = tile % TXN;
    int y0 = ty * 8, x0 = tx * 16;
    int ob = blockIdx.y * 256;
    int b = blockIdx.z;

    __shared__ __align__(16) _Float16 Xs[180 * 32];      // [sy*18+sx][32ic] 64B rows
    __shared__ __align__(16) _Float16 Wsb[2][256 * 32];  // [oc][32k] 64B rows

    int tid = threadIdx.x;
    int wid = tid >> 6, lane = tid & 63;
    int lr = lane & 15, lg = lane >> 4;

    f32x4 acc[8][4] = {};

    // staging thread geometry
    int sy = tid / 18, sx = tid - sy * 18;
    int gy = y0 + sy - 1, gx = x0 + sx - 1;
    bool act = tid < 180;
    bool ok = act && gy >= 0 && gy < H && gx >= 0 && gx < W;
    const float* inb = in + (size_t)b * 128 * H * W;
    const float* gp = inb + (size_t)gy * W + gx;

    // prologue: weight tile 0 -> regs
    int4 wreg[4];
    {
        const int4* wsrc = (const int4*)(Wcv + (size_t)ob * 32);
        #pragma unroll
        for (int j = 0; j < 4; ++j) wreg[j] = wsrc[j * 256 + tid];
    }

    int kg = 0;
    for (int ics = 0; ics < 4; ++ics) {
        if (ics) __syncthreads();  // all reads of previous Xs slice done
        if (act) {
            _Float16 hv[32];
            if (ok) {
                #pragma unroll
                for (int ic = 0; ic < 32; ++ic)
                    hv[ic] = (_Float16)gp[(size_t)(ics * 32 + ic) * H * W];
            } else {
                #pragma unroll
                for (int ic = 0; ic < 32; ++ic) hv[ic] = (_Float16)0.f;
            }
            #pragma unroll
            for (int s = 0; s < 4; ++s) {
                int ls = s ^ (tid & 3);
                hfrag hh;
                #pragma unroll
                for (int e = 0; e < 8; ++e) hh[e] = hv[ls * 8 + e];
                *(hfrag*)(&Xs[tid * 32 + s * 8]) = hh;
            }
        }
        for (int tap = 0; tap < 9; ++tap, ++kg) {
            _Float16* Wb = Wsb[kg & 1];
            #pragma unroll
            for (int j = 0; j < 4; ++j)
                *(int4*)((char*)Wb + (j * 256 + tid) * 16) = wreg[j];
            if (kg < 35) {
                const int4* wsrc = (const int4*)(Wcv + (size_t)(kg + 1) * 512 * 32 + (size_t)ob * 32);
                #pragma unroll
                for (int j = 0; j < 4; ++j) wreg[j] = wsrc[j * 256 + tid];
            }
            __syncthreads();
            hfrag af[4], bf[8];
            #pragma unroll
            for (int n = 0; n < 4; ++n) {
                int row = (wid * 4 + n) * 16 + lr;
                af[n] = *(const hfrag*)((char*)Wb + row * 64 + ((lg << 4) ^ ((row & 3) << 4)));
            }
            int dy = tap / 3, dx = tap - dy * 3;
            #pragma unroll
            for (int m = 0; m < 8; ++m) {
                int row = (m + dy) * 18 + lr + dx;
                bf[m] = *(const hfrag*)((char*)Xs + row * 64 + ((lg << 4) ^ ((row & 3) << 4)));
            }
            #pragma unroll
            for (int m = 0; m < 8; ++m)
                #pragma unroll
                for (int n = 0; n < 4; ++n)
                    acc[m][n] = MFMA16H(af[n], bf[m], acc[m][n], 0, 0, 0);
        }
    }

    // epilogue: PixelShuffle-fused residual RMW (coalesced float2 rows)
    float* outb = out + (size_t)b * 128 * 4 * H * W;
    #pragma unroll
    for (int m = 0; m < 8; ++m) {
        int py = y0 + m;
        int px = x0 + lr;
        #pragma unroll
        for (int n = 0; n < 4; ++n) {
            int oc0 = ob + (wid * 4 + n) * 16 + lg * 4;
            int c = oc0 >> 2;
            #pragma unroll
            for (int i2 = 0; i2 < 2; ++i2) {
                size_t oidx = ((size_t)c * (2 * H) + 2 * py + i2) * (2 * W) + 2 * px;
                float2* p = (float2*)(outb + oidx);
                float2 v = *p;
                v.x += acc[m][n][i2 * 2 + 0];
                v.y += acc[m][n][i2 * 2 + 1];
                *p = v;
            }
        }
    }
}

extern "C" void kernel_launch(void* const* d_in, const int* in_sizes, int n_in,
                              void* d_out, int out_size, void* d_ws, size_t ws_size,
                              hipStream_t stream) {
    const float* f0 = (const float*)d_in[0];
    const float* f1 = (const float*)d_in[1];
    const float* f2 = (const float*)d_in[2];
    const float* Wq = (const float*)d_in[3];
    const float* Wk = (const float*)d_in[4];
    const float* Wv = (const float*)d_in[5];
    const float* Wql = (const float*)d_in[6];
    const float* Wkl = (const float*)d_in[7];
    const float* Wvl = (const float*)d_in[8];
    const float* gate_w = (const float*)d_in[9];
    const float* conv0 = (const float*)d_in[10];
    const float* conv1 = (const float*)d_in[11];
    float* out = (float*)d_out;
    float* ws = (float*)d_ws;

    float* Mglob = ws;                    // 16384
    float* ctr = Mglob + 16384;           // 688128
    float* Tg = ctr + 688128;             // 688128
    float* Vg = Tg + 688128;              // 688128
    float* ycen = Vg + 688128;            // 688128
    unsigned short* MtB = (unsigned short*)(ycen + 688128);  // 16384 bf16
    unsigned short* WvltB = MtB + 16384;                     // 16384 bf16
    unsigned short* G1tB = WvltB + 16384;                    // 16384 bf16
    _Float16* Wcv0 = (_Float16*)(G1tB + 16384);              // 589824 f16
    _Float16* Wcv1 = Wcv0 + 589824;                          // 589824 f16

    hipFuncSetAttribute((const void*)k_local_mfma,
                        hipFuncAttributeMaxDynamicSharedMemorySize, SMEM_SZ);

    k_mm<<<dim3(128), 128, 0, stream>>>(Wq, Wk, Mglob);
    k_prep<<<dim3(128, 3), 128, 0, stream>>>(Wql, Wkl, Wvl, gate_w, MtB, WvltB, G1tB);
    k_prep_conv<<<dim3(2304, 2), 256, 0, stream>>>(conv0, conv1, Wcv0, Wcv1);
    k_centers<<<dim3(NWIN, 4), 256, 0, stream>>>(f0, f1, f2, ctr);
    k_tgvg<<<dim3(NWIN, 4), 128, 0, stream>>>(ctr, Mglob, Wv, Tg, Vg);
    k_gattn<<<dim3(NWIN, 4), 256, 0, stream>>>(ctr, Tg, Vg, ycen);
    k_local_mfma<<<dim3(NWIN, 4), 256, SMEM_SZ, stream>>>(
        f0, f1, f2, MtB, WvltB, G1tB, gate_w, ycen, out);
    k_conv_mfma<64, 64><<<dim3(32, 2, 4), 256, 0, stream>>>(out + OUT0, Wcv0, out + OUT1);
    k_conv_mfma<128, 128><<<dim3(128, 2, 4), 256, 0, stream>>>(out + OUT1, Wcv1, out + OUT2);
}

// Round 4
// 777.387 us; speedup vs baseline: 12.0854x; 1.5206x over previous
//
#include <hip/hip_runtime.h>
#include <math.h>

#define WT 64
#define NWIN 1344
#define NP 1408  // padded key dim for PV GEMM
constexpr float SCALE = 0.088388347648318447f;  // 128^-0.5

// out region offsets (floats)
#define OUT0 0
#define OUT1 2097152
#define OUT2 10485760

typedef __attribute__((ext_vector_type(8))) short bfrag;      // 8 bf16
typedef __attribute__((ext_vector_type(8))) _Float16 hfrag;   // 8 fp16
typedef __attribute__((ext_vector_type(4))) float f32x4;      // MFMA C/D

#define MFMA16 __builtin_amdgcn_mfma_f32_16x16x32_bf16
#define MFMA16H __builtin_amdgcn_mfma_f32_16x16x32_f16

__device__ __forceinline__ unsigned short f2b(float f) {
    union { float f; unsigned u; } v; v.f = f;
    unsigned r = v.u + 0x7fffu + ((v.u >> 16) & 1u);  // rne
    return (unsigned short)(r >> 16);
}
__device__ __forceinline__ float b2f(unsigned short u) {
    union { unsigned u; float f; } v; v.u = ((unsigned)u) << 16; return v.f;
}
__device__ __forceinline__ int pack2(float a, float b) {
    return (int)f2b(a) | ((int)f2b(b) << 16);
}

// swizzled LDS fragment loads: row-major bf16 tiles, byte ^= (row&7)<<4
__device__ __forceinline__ bfrag ld256(const char* region, int row, int k) {
    int off = (2 * k) ^ ((row & 7) << 4);
    return *(const bfrag*)(region + row * 256 + off);
}
__device__ __forceinline__ bfrag ld128(const char* region, int row, int k) {
    int off = (2 * k) ^ ((row & 7) << 4);
    return *(const bfrag*)(region + row * 128 + off);
}

// K1: Mglob = Wq @ Wk^T (fp32, global path)
__global__ void k_mm(const float* __restrict__ Wq, const float* __restrict__ Wk,
                     float* __restrict__ Mglob) {
    int i = blockIdx.x, j = threadIdx.x;
    float acc = 0.f;
    for (int k = 0; k < 128; ++k) acc += Wq[i * 128 + k] * Wk[j * 128 + k];
    Mglob[i * 128 + j] = acc;
}

// K1b: bf16 transposed weight prep for local path.
__global__ void k_prep(const float* __restrict__ Wql, const float* __restrict__ Wkl,
                       const float* __restrict__ Wvl, const float* __restrict__ gw,
                       unsigned short* __restrict__ MtB,
                       unsigned short* __restrict__ WvltB,
                       unsigned short* __restrict__ G1tB) {
    int n = blockIdx.x, k = threadIdx.x;
    if (blockIdx.y == 0) {
        float a = 0.f;
        for (int c = 0; c < 128; ++c) a += Wkl[n * 128 + c] * Wql[k * 128 + c];
        MtB[n * 128 + k] = f2b(a);
    } else if (blockIdx.y == 1) {
        WvltB[n * 128 + k] = f2b(Wvl[k * 128 + n]);
    } else {
        G1tB[n * 128 + k] = f2b(gw[(128 + k) * 128 + n]);
    }
}

// K1c: conv weight prep -> fp16 "LDS image" layout [36][512][32]
__global__ __launch_bounds__(256) void k_prep_conv(
    const float* __restrict__ w0, const float* __restrict__ w1,
    _Float16* __restrict__ W0, _Float16* __restrict__ W1) {
    int idx = blockIdx.x * 256 + threadIdx.x;  // < 589824 = 36*512*32
    const float* w = blockIdx.y ? w1 : w0;
    _Float16* o = blockIdx.y ? W1 : W0;
    int t = idx & 31, oc = (idx >> 5) & 511, slice = idx >> 14;
    int ics = slice / 9, tap = slice % 9;
    int s = t >> 3, e = t & 7;
    int ic = ics * 32 + ((s ^ (oc & 3)) * 8 + e);
    o[idx] = (_Float16)w[((size_t)oc * 128 + ic) * 9 + tap];
}

__device__ __forceinline__ void window_src(int n0, const float* f0, const float* f1,
                                           const float* f2, const float*& f, int& p0,
                                           int& HW, int& obase) {
    if (n0 < 4096)        { f = f0; p0 = n0;          HW = 4096;  obase = OUT0; }
    else if (n0 < 20480)  { f = f1; p0 = n0 - 4096;   HW = 16384; obase = OUT1; }
    else                  { f = f2; p0 = n0 - 20480;  HW = 65536; obase = OUT2; }
}

// K2: window means -> centers f32 [B,NWIN,128] + bf16 copy
__global__ __launch_bounds__(256) void k_centers(
    const float* __restrict__ f0, const float* __restrict__ f1,
    const float* __restrict__ f2, float* __restrict__ ctr,
    unsigned short* __restrict__ ctrb) {
    int w = blockIdx.x, b = blockIdx.y;
    const float* f; int p0, HW, ob;
    window_src(w * WT, f0, f1, f2, f, p0, HW, ob);
    int lane = threadIdx.x & 63, cg = threadIdx.x >> 6;
    for (int c = cg; c < 128; c += 4) {
        float v = f[(b * 128 + c) * HW + p0 + lane];
        #pragma unroll
        for (int off = 32; off; off >>= 1) v += __shfl_xor(v, off);
        if (lane == 0) {
            float mv = v * (1.0f / 64.0f);
            ctr[(b * NWIN + w) * 128 + c] = mv;
            ctrb[(b * NWIN + w) * 128 + c] = f2b(mv);
        }
    }
}

// K3: Tgb = bf16(centers @ Mglob) ; Vgt = bf16((centers @ Wv)^T) [c][NP]
__global__ __launch_bounds__(128) void k_tgvg(
    const float* __restrict__ ctr, const float* __restrict__ Mglob,
    const float* __restrict__ Wv, unsigned short* __restrict__ Tgb,
    unsigned short* __restrict__ Vgt) {
    int n = blockIdx.x, b = blockIdx.y;
    int row = b * NWIN + n;
    int c = threadIdx.x;
    __shared__ __align__(16) float crow[128];
    crow[c] = ctr[row * 128 + c];
    __syncthreads();
    float a1 = 0.f, a2 = 0.f;
    for (int k = 0; k < 128; ++k) {
        float cv = crow[k];
        a1 += cv * Mglob[k * 128 + c];
        a2 += cv * Wv[k * 128 + c];
    }
    Tgb[row * 128 + c] = f2b(a1);
    Vgt[((size_t)b * 128 + c) * NP + n] = f2b(a2);
}

// K4a: global scores + fused row softmax -> P bf16 [b][NWIN][NP] (pad zeroed)
// Block: 32 query rows x all 1344 keys. MFMA frags loaded straight from L2.
__global__ __launch_bounds__(256, 1) void k_qk(
    const unsigned short* __restrict__ Tgb, const unsigned short* __restrict__ ctrb,
    unsigned short* __restrict__ P) {
    extern __shared__ unsigned short Srow[];  // [32][1344] bf16 raw scores
    __shared__ float mxs[32], invs[32];
    int blk = blockIdx.x, b = blockIdx.y;
    int mb = blk * 32;
    int tid = threadIdx.x, wid = tid >> 6, lane = tid & 63;
    int lr = lane & 15, lg = lane >> 4;
    int wm = (wid & 1) * 16, wn = (wid >> 1) * 32;

    const unsigned short* Arow = Tgb + ((size_t)b * NWIN + mb + wm + lr) * 128;
    for (int tile = 0; tile < 21; ++tile) {
        int nb = tile * 64 + wn;
        f32x4 acc[2] = {};
        #pragma unroll
        for (int ks = 0; ks < 4; ++ks) {
            int k = ks * 32 + lg * 8;
            bfrag a = *(const bfrag*)(Arow + k);
            #pragma unroll
            for (int nt = 0; nt < 2; ++nt) {
                bfrag bb = *(const bfrag*)(ctrb + ((size_t)b * NWIN + nb + nt * 16 + lr) * 128 + k);
                acc[nt] = MFMA16(a, bb, acc[nt], 0, 0, 0);
            }
        }
        #pragma unroll
        for (int nt = 0; nt < 2; ++nt) {
            int col = nb + nt * 16 + lr;
            #pragma unroll
            for (int r = 0; r < 4; ++r) {
                int mrow = wm + 4 * lg + r;
                Srow[mrow * 1344 + col] = f2b(acc[nt][r]);
            }
        }
    }
    __syncthreads();
    {   // row max + sum(exp): 8 threads per row
        int row = tid >> 3, sub = tid & 7;
        const unsigned short* sr = Srow + row * 1344;
        float mx = -1e30f;
        for (int c = sub; c < 1344; c += 8) mx = fmaxf(mx, b2f(sr[c]));
        mx = fmaxf(mx, __shfl_xor(mx, 1));
        mx = fmaxf(mx, __shfl_xor(mx, 2));
        mx = fmaxf(mx, __shfl_xor(mx, 4));
        float sum = 0.f;
        for (int c = sub; c < 1344; c += 8) sum += __expf((b2f(sr[c]) - mx) * SCALE);
        sum += __shfl_xor(sum, 1);
        sum += __shfl_xor(sum, 2);
        sum += __shfl_xor(sum, 4);
        if (sub == 0) { mxs[row] = mx; invs[row] = 1.0f / sum; }
    }
    __syncthreads();
    // normalized P, coalesced int4 writes, pad cols zeroed
    unsigned short* Pb = P + ((size_t)b * NWIN + mb) * NP;
    for (int idx = tid; idx < 32 * (NP / 8); idx += 256) {
        int row = idx / (NP / 8), c8 = idx % (NP / 8);
        float mx = mxs[row], inv = invs[row];
        unsigned short o[8];
        #pragma unroll
        for (int e = 0; e < 8; ++e) {
            int c = c8 * 8 + e;
            float p = (c < 1344) ? __expf((b2f(Srow[row * 1344 + c]) - mx) * SCALE) * inv : 0.f;
            o[e] = f2b(p);
        }
        *(int4*)(Pb + row * NP + c8 * 8) = *(int4*)o;
    }
}

// K4b: Y^T = Vgt x P^T (register-only MFMA GEMM); ycen = Y * centers
__global__ __launch_bounds__(256) void k_pv(
    const unsigned short* __restrict__ P, const unsigned short* __restrict__ Vgt,
    const float* __restrict__ ctr, float* __restrict__ ycen) {
    int blk = blockIdx.x, b = blockIdx.y;
    int mb = blk * 32;
    int tid = threadIdx.x, wid = tid >> 6, lane = tid & 63;
    int lr = lane & 15, lg = lane >> 4;
    int cb = wid * 32;
    f32x4 acc[2][2] = {};  // [ci][mj]
    const unsigned short* Pb = P + ((size_t)b * NWIN + mb) * NP;
    const unsigned short* Vb = Vgt + (size_t)b * 128 * NP;
    for (int it = 0; it < 44; ++it) {
        int k = it * 32 + lg * 8;
        bfrag a0 = *(const bfrag*)(Vb + (size_t)(cb + lr) * NP + k);
        bfrag a1 = *(const bfrag*)(Vb + (size_t)(cb + 16 + lr) * NP + k);
        bfrag b0 = *(const bfrag*)(Pb + (size_t)lr * NP + k);
        bfrag b1 = *(const bfrag*)(Pb + (size_t)(16 + lr) * NP + k);
        acc[0][0] = MFMA16(a0, b0, acc[0][0], 0, 0, 0);
        acc[0][1] = MFMA16(a0, b1, acc[0][1], 0, 0, 0);
        acc[1][0] = MFMA16(a1, b0, acc[1][0], 0, 0, 0);
        acc[1][1] = MFMA16(a1, b1, acc[1][1], 0, 0, 0);
    }
    #pragma unroll
    for (int ci = 0; ci < 2; ++ci)
        #pragma unroll
        for (int mj = 0; mj < 2; ++mj) {
            int c0 = cb + ci * 16 + 4 * lg;
            int m = mb + mj * 16 + lr;
            size_t base = ((size_t)b * NWIN + m) * 128 + c0;
            float4 cv = *(const float4*)(ctr + base);
            float4 y;
            y.x = acc[ci][mj][0] * cv.x;
            y.y = acc[ci][mj][1] * cv.y;
            y.z = acc[ci][mj][2] * cv.z;
            y.w = acc[ci][mj][3] * cv.w;
            *(float4*)(ycen + base) = y;
        }
}

// ---------- K5: fused local window attention via MFMA ----------
#define XB_OFF 0
#define WT_OFF 16384
#define XM_OFF 49152
#define PB_OFF 65536
#define VT_OFF 73728
#define YG_OFF 90112
#define G0_OFF 90624
#define SMEM_SZ 91136

__global__ __launch_bounds__(256, 1) void k_local_mfma(
    const float* __restrict__ f0, const float* __restrict__ f1,
    const float* __restrict__ f2,
    const unsigned short* __restrict__ MtB,
    const unsigned short* __restrict__ WvltB,
    const unsigned short* __restrict__ G1tB,
    const float* __restrict__ gw, const float* __restrict__ ycen,
    float* __restrict__ out) {
    extern __shared__ char smem[];
    char* Xb = smem + XB_OFF;
    char* Wt = smem + WT_OFF;
    char* XMb = smem + XM_OFF;
    char* Pb = smem + PB_OFF;
    char* Vt = smem + VT_OFF;
    float* ygs = (float*)(smem + YG_OFF);
    float* g0s = (float*)(smem + G0_OFF);

    int w = blockIdx.x, b = blockIdx.y;
    const float* f; int p0, HW, obase;
    window_src(w * WT, f0, f1, f2, f, p0, HW, obase);

    int tid = threadIdx.x;
    int wid = tid >> 6, lane = tid & 63;
    int lr = lane & 15, lg = lane >> 4;

    {
        int t = tid & 63, cq = tid >> 6;
        const float* src = f + (size_t)(b * 128 + cq * 32) * HW + p0 + t;
        float xv[32];
        #pragma unroll
        for (int i = 0; i < 32; ++i) xv[i] = src[(size_t)i * HW];
        int4 wreg[8];
        const int4* wsrc = (const int4*)MtB;
        #pragma unroll
        for (int j = 0; j < 8; ++j) wreg[j] = wsrc[j * 256 + tid];
        if (tid < 128) {
            const float* ygrow = ycen + ((size_t)b * NWIN + w) * 128;
            ygs[tid] = ygrow[tid];
            float a = 0.f;
            for (int c = 0; c < 128; ++c) a += ygrow[c] * gw[c * 128 + tid];
            g0s[tid] = a;
        }
        #pragma unroll
        for (int j = 0; j < 4; ++j) {
            int c0 = cq * 32 + j * 8;
            int4 v;
            v.x = pack2(xv[j * 8 + 0], xv[j * 8 + 1]);
            v.y = pack2(xv[j * 8 + 2], xv[j * 8 + 3]);
            v.z = pack2(xv[j * 8 + 4], xv[j * 8 + 5]);
            v.w = pack2(xv[j * 8 + 6], xv[j * 8 + 7]);
            *(int4*)(Xb + t * 256 + ((2 * c0) ^ ((t & 7) << 4))) = v;
        }
        #pragma unroll
        for (int j = 0; j < 8; ++j) {
            int ci = j * 256 + tid, n = ci >> 4, pos = ci & 15;
            *(int4*)(Wt + n * 256 + ((pos * 16) ^ ((n & 7) << 4))) = wreg[j];
        }
    }
    __syncthreads();

    int t = 16 * wid + lr;

    {   // phase 1: XM^T
        f32x4 acc[8] = {};
        #pragma unroll
        for (int ks = 0; ks < 4; ++ks) {
            int k = ks * 32 + lg * 8;
            bfrag xb = ld256(Xb, t, k);
            #pragma unroll
            for (int ct = 0; ct < 8; ++ct) {
                bfrag am = ld256(Wt, 16 * ct + lr, k);
                acc[ct] = MFMA16(am, xb, acc[ct], 0, 0, 0);
            }
        }
        #pragma unroll
        for (int ct = 0; ct < 8; ++ct) {
            int c0 = 16 * ct + 4 * lg;
            int2 v; v.x = pack2(acc[ct][0], acc[ct][1]); v.y = pack2(acc[ct][2], acc[ct][3]);
            *(int2*)(XMb + t * 256 + ((2 * c0) ^ ((t & 7) << 4))) = v;
        }
    }
    __syncthreads();

    {   // phase 2: S^T + softmax
        int4 wreg[8];
        const int4* wsrc = (const int4*)WvltB;
        #pragma unroll
        for (int j = 0; j < 8; ++j) wreg[j] = wsrc[j * 256 + tid];

        f32x4 s[4] = {};
        #pragma unroll
        for (int ks = 0; ks < 4; ++ks) {
            int k = ks * 32 + lg * 8;
            bfrag bxm = ld256(XMb, t, k);
            #pragma unroll
            for (int ut = 0; ut < 4; ++ut) {
                bfrag ax = ld256(Xb, 16 * ut + lr, k);
                s[ut] = MFMA16(ax, bxm, s[ut], 0, 0, 0);
            }
        }
        float m = -1e30f;
        #pragma unroll
        for (int ut = 0; ut < 4; ++ut)
            #pragma unroll
            for (int r = 0; r < 4; ++r) m = fmaxf(m, s[ut][r]);
        m = fmaxf(m, __shfl_xor(m, 16));
        m = fmaxf(m, __shfl_xor(m, 32));
        float sum = 0.f;
        float e[4][4];
        #pragma unroll
        for (int ut = 0; ut < 4; ++ut)
            #pragma unroll
            for (int r = 0; r < 4; ++r) {
                e[ut][r] = __expf((s[ut][r] - m) * SCALE);
                sum += e[ut][r];
            }
        sum += __shfl_xor(sum, 16);
        sum += __shfl_xor(sum, 32);
        float pinv = 1.0f / sum;
        #pragma unroll
        for (int ut = 0; ut < 4; ++ut) {
            int u0 = 16 * ut + 4 * lg;
            int2 v;
            v.x = pack2(e[ut][0] * pinv, e[ut][1] * pinv);
            v.y = pack2(e[ut][2] * pinv, e[ut][3] * pinv);
            *(int2*)(Pb + t * 128 + ((2 * u0) ^ ((t & 7) << 4))) = v;
        }
        #pragma unroll
        for (int j = 0; j < 8; ++j) {
            int ci = j * 256 + tid, n = ci >> 4, pos = ci & 15;
            *(int4*)(Wt + n * 256 + ((pos * 16) ^ ((n & 7) << 4))) = wreg[j];
        }
    }
    __syncthreads();

    {   // phase 3: V^T
        f32x4 vacc[8] = {};
        #pragma unroll
        for (int ks = 0; ks < 4; ++ks) {
            int k = ks * 32 + lg * 8;
            bfrag ax = ld256(Xb, t, k);
            #pragma unroll
            for (int ct = 0; ct < 8; ++ct) {
                bfrag bw = ld256(Wt, 16 * ct + lr, k);
                vacc[ct] = MFMA16(ax, bw, vacc[ct], 0, 0, 0);
            }
        }
        #pragma unroll
        for (int ct = 0; ct < 8; ++ct) {
            int c = 16 * ct + lr;
            int u0 = 16 * wid + 4 * lg;
            int2 v; v.x = pack2(vacc[ct][0], vacc[ct][1]); v.y = pack2(vacc[ct][2], vacc[ct][3]);
            *(int2*)(Vt + c * 128 + ((2 * u0) ^ ((c & 7) << 4))) = v;
        }
    }
    __syncthreads();

    float yl[8][4];
    {   // phase 4: Y^T = Vt x P ; yl = Y*X
        int4 wreg[8];
        const int4* wsrc = (const int4*)G1tB;
        #pragma unroll
        for (int j = 0; j < 8; ++j) wreg[j] = wsrc[j * 256 + tid];

        f32x4 y[8] = {};
        #pragma unroll
        for (int us = 0; us < 2; ++us) {
            int u = us * 32 + lg * 8;
            bfrag bp = ld128(Pb, t, u);
            #pragma unroll
            for (int ct = 0; ct < 8; ++ct) {
                bfrag av = ld128(Vt, 16 * ct + lr, u);
                y[ct] = MFMA16(av, bp, y[ct], 0, 0, 0);
            }
        }
        char* ylb = XMb;
        #pragma unroll
        for (int ct = 0; ct < 8; ++ct) {
            int c0 = 16 * ct + 4 * lg;
            int2 xw = *(const int2*)(Xb + t * 256 + ((2 * c0) ^ ((t & 7) << 4)));
            float x0 = b2f((unsigned short)(xw.x & 0xffff));
            float x1 = b2f((unsigned short)((unsigned)xw.x >> 16));
            float x2 = b2f((unsigned short)(xw.y & 0xffff));
            float x3 = b2f((unsigned short)((unsigned)xw.y >> 16));
            yl[ct][0] = y[ct][0] * x0;
            yl[ct][1] = y[ct][1] * x1;
            yl[ct][2] = y[ct][2] * x2;
            yl[ct][3] = y[ct][3] * x3;
            int2 v; v.x = pack2(yl[ct][0], yl[ct][1]); v.y = pack2(yl[ct][2], yl[ct][3]);
            *(int2*)(ylb + t * 256 + ((2 * c0) ^ ((t & 7) << 4))) = v;
        }
        #pragma unroll
        for (int j = 0; j < 8; ++j) {
            int ci = j * 256 + tid, n = ci >> 4, pos = ci & 15;
            *(int4*)(Wt + n * 256 + ((pos * 16) ^ ((n & 7) << 4))) = wreg[j];
        }
    }
    __syncthreads();

    {   // phase 5: gate + blend + store
        const char* ylb = XMb;
        f32x4 g[8] = {};
        #pragma unroll
        for (int ks = 0; ks < 4; ++ks) {
            int k = ks * 32 + lg * 8;
            bfrag byl = ld256(ylb, t, k);
            #pragma unroll
            for (int nt = 0; nt < 8; ++nt) {
                bfrag ag = ld256(Wt, 16 * nt + lr, k);
                g[nt] = MFMA16(ag, byl, g[nt], 0, 0, 0);
            }
        }
        #pragma unroll
        for (int nt = 0; nt < 8; ++nt) {
            #pragma unroll
            for (int r = 0; r < 4; ++r) {
                int c = 16 * nt + 4 * lg + r;
                float a = 1.0f / (1.0f + __expf(-(g[nt][r] + g0s[c])));
                float yv = a * ygs[c] + (1.0f - a) * yl[nt][r];
                out[obase + (size_t)(b * 128 + c) * HW + p0 + t] = yv;
            }
        }
    }
}

// ---------- K6/K7: conv3x3(128->512) + PixelShuffle + residual, MFMA fp16 ----
template <int H, int W>
__global__ __launch_bounds__(256, 2) void k_conv_mfma(
    const float* __restrict__ in, const _Float16* __restrict__ Wcv,
    float* __restrict__ out) {
    constexpr int TXN = W / 16;
    int tile = blockIdx.x;
    int ty = tile / TXN, tx = tile % TXN;
    int y0 = ty * 8, x0 = tx * 16;
    int ob = blockIdx.y * 256;
    int b = blockIdx.z;

    __shared__ __align__(16) _Float16 Xs[180 * 32];      // [sy*18+sx][32ic] 64B rows
    __shared__ __align__(16) _Float16 Wsb[2][256 * 32];  // [oc][32k] 64B rows

    int tid = threadIdx.x;
    int wid = tid >> 6, lane = tid & 63;
    int lr = lane & 15, lg = lane >> 4;

    f32x4 acc[8][4] = {};

    int sy = tid / 18, sx = tid - sy * 18;
    int gy = y0 + sy - 1, gx = x0 + sx - 1;
    bool act = tid < 180;
    bool ok = act && gy >= 0 && gy < H && gx >= 0 && gx < W;
    const float* inb = in + (size_t)b * 128 * H * W;
    const float* gp = inb + (size_t)gy * W + gx;

    int4 wreg[4];
    {
        const int4* wsrc = (const int4*)(Wcv + (size_t)ob * 32);
        #pragma unroll
        for (int j = 0; j < 4; ++j) wreg[j] = wsrc[j * 256 + tid];
    }

    int kg = 0;
    for (int ics = 0; ics < 4; ++ics) {
        if (ics) __syncthreads();
        if (act) {
            _Float16 hv[32];
            if (ok) {
                #pragma unroll
                for (int ic = 0; ic < 32; ++ic)
                    hv[ic] = (_Float16)gp[(size_t)(ics * 32 + ic) * H * W];
            } else {
                #pragma unroll
                for (int ic = 0; ic < 32; ++ic) hv[ic] = (_Float16)0.f;
            }
            #pragma unroll
            for (int s = 0; s < 4; ++s) {
                int ls = s ^ (tid & 3);
                hfrag hh;
                #pragma unroll
                for (int e = 0; e < 8; ++e) hh[e] = hv[ls * 8 + e];
                *(hfrag*)(&Xs[tid * 32 + s * 8]) = hh;
            }
        }
        for (int tap = 0; tap < 9; ++tap, ++kg) {
            _Float16* Wb = Wsb[kg & 1];
            #pragma unroll
            for (int j = 0; j < 4; ++j)
                *(int4*)((char*)Wb + (j * 256 + tid) * 16) = wreg[j];
            if (kg < 35) {
                const int4* wsrc = (const int4*)(Wcv + (size_t)(kg + 1) * 512 * 32 + (size_t)ob * 32);
                #pragma unroll
                for (int j = 0; j < 4; ++j) wreg[j] = wsrc[j * 256 + tid];
            }
            __syncthreads();
            hfrag af[4], bf[8];
            #pragma unroll
            for (int n = 0; n < 4; ++n) {
                int row = (wid * 4 + n) * 16 + lr;
                af[n] = *(const hfrag*)((char*)Wb + row * 64 + ((lg << 4) ^ ((row & 3) << 4)));
            }
            int dy = tap / 3, dx = tap - dy * 3;
            #pragma unroll
            for (int m = 0; m < 8; ++m) {
                int row = (m + dy) * 18 + lr + dx;
                bf[m] = *(const hfrag*)((char*)Xs + row * 64 + ((lg << 4) ^ ((row & 3) << 4)));
            }
            #pragma unroll
            for (int m = 0; m < 8; ++m)
                #pragma unroll
                for (int n = 0; n < 4; ++n)
                    acc[m][n] = MFMA16H(af[n], bf[m], acc[m][n], 0, 0, 0);
        }
    }

    float* outb = out + (size_t)b * 128 * 4 * H * W;
    #pragma unroll
    for (int m = 0; m < 8; ++m) {
        int py = y0 + m;
        int px = x0 + lr;
        #pragma unroll
        for (int n = 0; n < 4; ++n) {
            int oc0 = ob + (wid * 4 + n) * 16 + lg * 4;
            int c = oc0 >> 2;
            #pragma unroll
            for (int i2 = 0; i2 < 2; ++i2) {
                size_t oidx = ((size_t)c * (2 * H) + 2 * py + i2) * (2 * W) + 2 * px;
                float2* p = (float2*)(outb + oidx);
                float2 v = *p;
                v.x += acc[m][n][i2 * 2 + 0];
                v.y += acc[m][n][i2 * 2 + 1];
                *p = v;
            }
        }
    }
}

extern "C" void kernel_launch(void* const* d_in, const int* in_sizes, int n_in,
                              void* d_out, int out_size, void* d_ws, size_t ws_size,
                              hipStream_t stream) {
    const float* f0 = (const float*)d_in[0];
    const float* f1 = (const float*)d_in[1];
    const float* f2 = (const float*)d_in[2];
    const float* Wq = (const float*)d_in[3];
    const float* Wk = (const float*)d_in[4];
    const float* Wv = (const float*)d_in[5];
    const float* Wql = (const float*)d_in[6];
    const float* Wkl = (const float*)d_in[7];
    const float* Wvl = (const float*)d_in[8];
    const float* gate_w = (const float*)d_in[9];
    const float* conv0 = (const float*)d_in[10];
    const float* conv1 = (const float*)d_in[11];
    float* out = (float*)d_out;
    float* ws = (float*)d_ws;

    float* Mglob = ws;                    // 16384 f32
    float* ctr = Mglob + 16384;           // 688128 f32
    float* ycen = ctr + 688128;           // 688128 f32
    unsigned short* MtB = (unsigned short*)(ycen + 688128);  // 16384 bf16
    unsigned short* WvltB = MtB + 16384;                     // 16384 bf16
    unsigned short* G1tB = WvltB + 16384;                    // 16384 bf16
    _Float16* Wcv0 = (_Float16*)(G1tB + 16384);              // 589824 f16
    _Float16* Wcv1 = Wcv0 + 589824;                          // 589824 f16
    unsigned short* ctrb = (unsigned short*)(Wcv1 + 589824); // 688128 bf16
    unsigned short* Tgb = ctrb + 688128;                     // 688128 bf16
    unsigned short* Vgt = Tgb + 688128;                      // 4*128*NP bf16
    unsigned short* Pg = Vgt + 4 * 128 * NP;                 // 4*NWIN*NP bf16

    hipFuncSetAttribute((const void*)k_local_mfma,
                        hipFuncAttributeMaxDynamicSharedMemorySize, SMEM_SZ);
    hipFuncSetAttribute((const void*)k_qk,
                        hipFuncAttributeMaxDynamicSharedMemorySize, 32 * 1344 * 2);

    k_mm<<<dim3(128), 128, 0, stream>>>(Wq, Wk, Mglob);
    k_prep<<<dim3(128, 3), 128, 0, stream>>>(Wql, Wkl, Wvl, gate_w, MtB, WvltB, G1tB);
    k_prep_conv<<<dim3(2304, 2), 256, 0, stream>>>(conv0, conv1, Wcv0, Wcv1);
    k_centers<<<dim3(NWIN, 4), 256, 0, stream>>>(f0, f1, f2, ctr, ctrb);
    k_tgvg<<<dim3(NWIN, 4), 128, 0, stream>>>(ctr, Mglob, Wv, Tgb, Vgt);
    k_qk<<<dim3(NWIN / 32, 4), 256, 32 * 1344 * 2, stream>>>(Tgb, ctrb, Pg);
    k_pv<<<dim3(NWIN / 32, 4), 256, 0, stream>>>(Pg, Vgt, ctr, ycen);
    k_local_mfma<<<dim3(NWIN, 4), 256, SMEM_SZ, stream>>>(
        f0, f1, f2, MtB, WvltB, G1tB, gate_w, ycen, out);
    k_conv_mfma<64, 64><<<dim3(32, 2, 4), 256, 0, stream>>>(out + OUT0, Wcv0, out + OUT1);
    k_conv_mfma<128, 128><<<dim3(128, 2, 4), 256, 0, stream>>>(out + OUT1, Wcv1, out + OUT2);
}

// Round 5
// 728.159 us; speedup vs baseline: 12.9025x; 1.0676x over previous
//
#include <hip/hip_runtime.h>
#include <math.h>

#define WT 64
#define NWIN 1344
#define NP 1408  // padded key dim for PV GEMM
constexpr float SCALE = 0.088388347648318447f;  // 128^-0.5

// out region offsets (floats)
#define OUT0 0
#define OUT1 2097152
#define OUT2 10485760

typedef __attribute__((ext_vector_type(8))) short bfrag;      // 8 bf16
typedef __attribute__((ext_vector_type(8))) _Float16 hfrag;   // 8 fp16
typedef __attribute__((ext_vector_type(4))) float f32x4;      // MFMA C/D

#define MFMA16 __builtin_amdgcn_mfma_f32_16x16x32_bf16
#define MFMA16H __builtin_amdgcn_mfma_f32_16x16x32_f16

__device__ __forceinline__ unsigned short f2b(float f) {
    union { float f; unsigned u; } v; v.f = f;
    unsigned r = v.u + 0x7fffu + ((v.u >> 16) & 1u);  // rne
    return (unsigned short)(r >> 16);
}
__device__ __forceinline__ float b2f(unsigned short u) {
    union { unsigned u; float f; } v; v.u = ((unsigned)u) << 16; return v.f;
}
__device__ __forceinline__ int pack2(float a, float b) {
    return (int)f2b(a) | ((int)f2b(b) << 16);
}

// swizzled LDS fragment loads: row-major bf16 tiles, byte ^= (row&7)<<4
__device__ __forceinline__ bfrag ld256(const char* region, int row, int k) {
    int off = (2 * k) ^ ((row & 7) << 4);
    return *(const bfrag*)(region + row * 256 + off);
}
__device__ __forceinline__ bfrag ld128(const char* region, int row, int k) {
    int off = (2 * k) ^ ((row & 7) << 4);
    return *(const bfrag*)(region + row * 128 + off);
}

// K1: Mglob = Wq @ Wk^T (fp32, global path)
__global__ void k_mm(const float* __restrict__ Wq, const float* __restrict__ Wk,
                     float* __restrict__ Mglob) {
    int i = blockIdx.x, j = threadIdx.x;
    float acc = 0.f;
    for (int k = 0; k < 128; ++k) acc += Wq[i * 128 + k] * Wk[j * 128 + k];
    Mglob[i * 128 + j] = acc;
}

// K1b: bf16 transposed weight prep for local path.
__global__ void k_prep(const float* __restrict__ Wql, const float* __restrict__ Wkl,
                       const float* __restrict__ Wvl, const float* __restrict__ gw,
                       unsigned short* __restrict__ MtB,
                       unsigned short* __restrict__ WvltB,
                       unsigned short* __restrict__ G1tB) {
    int n = blockIdx.x, k = threadIdx.x;
    if (blockIdx.y == 0) {
        float a = 0.f;
        for (int c = 0; c < 128; ++c) a += Wkl[n * 128 + c] * Wql[k * 128 + c];
        MtB[n * 128 + k] = f2b(a);
    } else if (blockIdx.y == 1) {
        WvltB[n * 128 + k] = f2b(Wvl[k * 128 + n]);
    } else {
        G1tB[n * 128 + k] = f2b(gw[(128 + k) * 128 + n]);
    }
}

// K1c: conv weight prep -> fp16 LDS image [36 slices][512 oc x 32 k]
// LDS image row oc (64B), phys slot p (16B) holds k-chunk (p ^ ((oc>>2)&3))*8.
__global__ __launch_bounds__(256) void k_prep_conv(
    const float* __restrict__ w0, const float* __restrict__ w1,
    _Float16* __restrict__ W0, _Float16* __restrict__ W1) {
    int idx = blockIdx.x * 256 + threadIdx.x;  // < 589824 = 36*512*32
    const float* w = blockIdx.y ? w1 : w0;
    _Float16* o = blockIdx.y ? W1 : W0;
    int slice = idx >> 14, rem = idx & 16383;
    int oc = rem >> 5, p = (rem >> 3) & 3, e = rem & 7;
    int k = ((p ^ ((oc >> 2) & 3)) << 3) | e;
    int ics = slice / 9, tap = slice - ics * 9;
    o[idx] = (_Float16)w[((size_t)oc * 128 + ics * 32 + k) * 9 + tap];
}

__device__ __forceinline__ void window_src(int n0, const float* f0, const float* f1,
                                           const float* f2, const float*& f, int& p0,
                                           int& HW, int& obase) {
    if (n0 < 4096)        { f = f0; p0 = n0;          HW = 4096;  obase = OUT0; }
    else if (n0 < 20480)  { f = f1; p0 = n0 - 4096;   HW = 16384; obase = OUT1; }
    else                  { f = f2; p0 = n0 - 20480;  HW = 65536; obase = OUT2; }
}

// K2: window means -> centers f32 [B,NWIN,128] + bf16 copy
__global__ __launch_bounds__(256) void k_centers(
    const float* __restrict__ f0, const float* __restrict__ f1,
    const float* __restrict__ f2, float* __restrict__ ctr,
    unsigned short* __restrict__ ctrb) {
    int w = blockIdx.x, b = blockIdx.y;
    const float* f; int p0, HW, ob;
    window_src(w * WT, f0, f1, f2, f, p0, HW, ob);
    int lane = threadIdx.x & 63, cg = threadIdx.x >> 6;
    for (int c = cg; c < 128; c += 4) {
        float v = f[(b * 128 + c) * HW + p0 + lane];
        #pragma unroll
        for (int off = 32; off; off >>= 1) v += __shfl_xor(v, off);
        if (lane == 0) {
            float mv = v * (1.0f / 64.0f);
            ctr[(b * NWIN + w) * 128 + c] = mv;
            ctrb[(b * NWIN + w) * 128 + c] = f2b(mv);
        }
    }
}

// K3: Tgb = bf16(centers @ Mglob) ; Vgt = bf16((centers @ Wv)^T) [c][NP]
__global__ __launch_bounds__(128) void k_tgvg(
    const float* __restrict__ ctr, const float* __restrict__ Mglob,
    const float* __restrict__ Wv, unsigned short* __restrict__ Tgb,
    unsigned short* __restrict__ Vgt) {
    int n = blockIdx.x, b = blockIdx.y;
    int row = b * NWIN + n;
    int c = threadIdx.x;
    __shared__ __align__(16) float crow[128];
    crow[c] = ctr[row * 128 + c];
    __syncthreads();
    float a1 = 0.f, a2 = 0.f;
    for (int k = 0; k < 128; ++k) {
        float cv = crow[k];
        a1 += cv * Mglob[k * 128 + c];
        a2 += cv * Wv[k * 128 + c];
    }
    Tgb[row * 128 + c] = f2b(a1);
    Vgt[((size_t)b * 128 + c) * NP + n] = f2b(a2);
}

// K4a: global scores + fused row softmax -> P bf16 [b][NWIN][NP] (pad zeroed)
__global__ __launch_bounds__(256, 1) void k_qk(
    const unsigned short* __restrict__ Tgb, const unsigned short* __restrict__ ctrb,
    unsigned short* __restrict__ P) {
    extern __shared__ unsigned short Srow[];  // [32][1344] bf16 raw scores
    __shared__ float mxs[32], invs[32];
    int blk = blockIdx.x, b = blockIdx.y;
    int mb = blk * 32;
    int tid = threadIdx.x, wid = tid >> 6, lane = tid & 63;
    int lr = lane & 15, lg = lane >> 4;
    int wm = (wid & 1) * 16, wn = (wid >> 1) * 32;

    const unsigned short* Arow = Tgb + ((size_t)b * NWIN + mb + wm + lr) * 128;
    for (int tile = 0; tile < 21; ++tile) {
        int nb = tile * 64 + wn;
        f32x4 acc[2] = {};
        #pragma unroll
        for (int ks = 0; ks < 4; ++ks) {
            int k = ks * 32 + lg * 8;
            bfrag a = *(const bfrag*)(Arow + k);
            #pragma unroll
            for (int nt = 0; nt < 2; ++nt) {
                bfrag bb = *(const bfrag*)(ctrb + ((size_t)b * NWIN + nb + nt * 16 + lr) * 128 + k);
                acc[nt] = MFMA16(a, bb, acc[nt], 0, 0, 0);
            }
        }
        #pragma unroll
        for (int nt = 0; nt < 2; ++nt) {
            int col = nb + nt * 16 + lr;
            #pragma unroll
            for (int r = 0; r < 4; ++r) {
                int mrow = wm + 4 * lg + r;
                Srow[mrow * 1344 + col] = f2b(acc[nt][r]);
            }
        }
    }
    __syncthreads();
    {   // row max + sum(exp): 8 threads per row
        int row = tid >> 3, sub = tid & 7;
        const unsigned short* sr = Srow + row * 1344;
        float mx = -1e30f;
        for (int c = sub; c < 1344; c += 8) mx = fmaxf(mx, b2f(sr[c]));
        mx = fmaxf(mx, __shfl_xor(mx, 1));
        mx = fmaxf(mx, __shfl_xor(mx, 2));
        mx = fmaxf(mx, __shfl_xor(mx, 4));
        float sum = 0.f;
        for (int c = sub; c < 1344; c += 8) sum += __expf((b2f(sr[c]) - mx) * SCALE);
        sum += __shfl_xor(sum, 1);
        sum += __shfl_xor(sum, 2);
        sum += __shfl_xor(sum, 4);
        if (sub == 0) { mxs[row] = mx; invs[row] = 1.0f / sum; }
    }
    __syncthreads();
    unsigned short* Pb = P + ((size_t)b * NWIN + mb) * NP;
    for (int idx = tid; idx < 32 * (NP / 8); idx += 256) {
        int row = idx / (NP / 8), c8 = idx % (NP / 8);
        float mx = mxs[row], inv = invs[row];
        unsigned short o[8];
        #pragma unroll
        for (int e = 0; e < 8; ++e) {
            int c = c8 * 8 + e;
            float p = (c < 1344) ? __expf((b2f(Srow[row * 1344 + c]) - mx) * SCALE) * inv : 0.f;
            o[e] = f2b(p);
        }
        *(int4*)(Pb + row * NP + c8 * 8) = *(int4*)o;
    }
}

// K4b: Y^T = Vgt x P^T (register-only MFMA GEMM); ycen = Y * centers
__global__ __launch_bounds__(256) void k_pv(
    const unsigned short* __restrict__ P, const unsigned short* __restrict__ Vgt,
    const float* __restrict__ ctr, float* __restrict__ ycen) {
    int blk = blockIdx.x, b = blockIdx.y;
    int mb = blk * 32;
    int tid = threadIdx.x, wid = tid >> 6, lane = tid & 63;
    int lr = lane & 15, lg = lane >> 4;
    int cb = wid * 32;
    f32x4 acc[2][2] = {};  // [ci][mj]
    const unsigned short* Pb = P + ((size_t)b * NWIN + mb) * NP;
    const unsigned short* Vb = Vgt + (size_t)b * 128 * NP;
    for (int it = 0; it < 44; ++it) {
        int k = it * 32 + lg * 8;
        bfrag a0 = *(const bfrag*)(Vb + (size_t)(cb + lr) * NP + k);
        bfrag a1 = *(const bfrag*)(Vb + (size_t)(cb + 16 + lr) * NP + k);
        bfrag b0 = *(const bfrag*)(Pb + (size_t)lr * NP + k);
        bfrag b1 = *(const bfrag*)(Pb + (size_t)(16 + lr) * NP + k);
        acc[0][0] = MFMA16(a0, b0, acc[0][0], 0, 0, 0);
        acc[0][1] = MFMA16(a0, b1, acc[0][1], 0, 0, 0);
        acc[1][0] = MFMA16(a1, b0, acc[1][0], 0, 0, 0);
        acc[1][1] = MFMA16(a1, b1, acc[1][1], 0, 0, 0);
    }
    #pragma unroll
    for (int ci = 0; ci < 2; ++ci)
        #pragma unroll
        for (int mj = 0; mj < 2; ++mj) {
            int c0 = cb + ci * 16 + 4 * lg;
            int m = mb + mj * 16 + lr;
            size_t base = ((size_t)b * NWIN + m) * 128 + c0;
            float4 cv = *(const float4*)(ctr + base);
            float4 y;
            y.x = acc[ci][mj][0] * cv.x;
            y.y = acc[ci][mj][1] * cv.y;
            y.z = acc[ci][mj][2] * cv.z;
            y.w = acc[ci][mj][3] * cv.w;
            *(float4*)(ycen + base) = y;
        }
}

// ---------- K5: fused local window attention via MFMA ----------
#define XB_OFF 0
#define WT_OFF 16384
#define XM_OFF 49152
#define PB_OFF 65536
#define VT_OFF 73728
#define YG_OFF 90112
#define G0_OFF 90624
#define SMEM_SZ 91136

__global__ __launch_bounds__(256, 1) void k_local_mfma(
    const float* __restrict__ f0, const float* __restrict__ f1,
    const float* __restrict__ f2,
    const unsigned short* __restrict__ MtB,
    const unsigned short* __restrict__ WvltB,
    const unsigned short* __restrict__ G1tB,
    const float* __restrict__ gw, const float* __restrict__ ycen,
    float* __restrict__ out) {
    extern __shared__ char smem[];
    char* Xb = smem + XB_OFF;
    char* Wt = smem + WT_OFF;
    char* XMb = smem + XM_OFF;
    char* Pb = smem + PB_OFF;
    char* Vt = smem + VT_OFF;
    float* ygs = (float*)(smem + YG_OFF);
    float* g0s = (float*)(smem + G0_OFF);

    int w = blockIdx.x, b = blockIdx.y;
    const float* f; int p0, HW, obase;
    window_src(w * WT, f0, f1, f2, f, p0, HW, obase);

    int tid = threadIdx.x;
    int wid = tid >> 6, lane = tid & 63;
    int lr = lane & 15, lg = lane >> 4;

    {
        int t = tid & 63, cq = tid >> 6;
        const float* src = f + (size_t)(b * 128 + cq * 32) * HW + p0 + t;
        float xv[32];
        #pragma unroll
        for (int i = 0; i < 32; ++i) xv[i] = src[(size_t)i * HW];
        int4 wreg[8];
        const int4* wsrc = (const int4*)MtB;
        #pragma unroll
        for (int j = 0; j < 8; ++j) wreg[j] = wsrc[j * 256 + tid];
        if (tid < 128) {
            const float* ygrow = ycen + ((size_t)b * NWIN + w) * 128;
            ygs[tid] = ygrow[tid];
            float a = 0.f;
            for (int c = 0; c < 128; ++c) a += ygrow[c] * gw[c * 128 + tid];
            g0s[tid] = a;
        }
        #pragma unroll
        for (int j = 0; j < 4; ++j) {
            int c0 = cq * 32 + j * 8;
            int4 v;
            v.x = pack2(xv[j * 8 + 0], xv[j * 8 + 1]);
            v.y = pack2(xv[j * 8 + 2], xv[j * 8 + 3]);
            v.z = pack2(xv[j * 8 + 4], xv[j * 8 + 5]);
            v.w = pack2(xv[j * 8 + 6], xv[j * 8 + 7]);
            *(int4*)(Xb + t * 256 + ((2 * c0) ^ ((t & 7) << 4))) = v;
        }
        #pragma unroll
        for (int j = 0; j < 8; ++j) {
            int ci = j * 256 + tid, n = ci >> 4, pos = ci & 15;
            *(int4*)(Wt + n * 256 + ((pos * 16) ^ ((n & 7) << 4))) = wreg[j];
        }
    }
    __syncthreads();

    int t = 16 * wid + lr;

    {   // phase 1: XM^T
        f32x4 acc[8] = {};
        #pragma unroll
        for (int ks = 0; ks < 4; ++ks) {
            int k = ks * 32 + lg * 8;
            bfrag xb = ld256(Xb, t, k);
            #pragma unroll
            for (int ct = 0; ct < 8; ++ct) {
                bfrag am = ld256(Wt, 16 * ct + lr, k);
                acc[ct] = MFMA16(am, xb, acc[ct], 0, 0, 0);
            }
        }
        #pragma unroll
        for (int ct = 0; ct < 8; ++ct) {
            int c0 = 16 * ct + 4 * lg;
            int2 v; v.x = pack2(acc[ct][0], acc[ct][1]); v.y = pack2(acc[ct][2], acc[ct][3]);
            *(int2*)(XMb + t * 256 + ((2 * c0) ^ ((t & 7) << 4))) = v;
        }
    }
    __syncthreads();

    {   // phase 2: S^T + softmax
        int4 wreg[8];
        const int4* wsrc = (const int4*)WvltB;
        #pragma unroll
        for (int j = 0; j < 8; ++j) wreg[j] = wsrc[j * 256 + tid];

        f32x4 s[4] = {};
        #pragma unroll
        for (int ks = 0; ks < 4; ++ks) {
            int k = ks * 32 + lg * 8;
            bfrag bxm = ld256(XMb, t, k);
            #pragma unroll
            for (int ut = 0; ut < 4; ++ut) {
                bfrag ax = ld256(Xb, 16 * ut + lr, k);
                s[ut] = MFMA16(ax, bxm, s[ut], 0, 0, 0);
            }
        }
        float m = -1e30f;
        #pragma unroll
        for (int ut = 0; ut < 4; ++ut)
            #pragma unroll
            for (int r = 0; r < 4; ++r) m = fmaxf(m, s[ut][r]);
        m = fmaxf(m, __shfl_xor(m, 16));
        m = fmaxf(m, __shfl_xor(m, 32));
        float sum = 0.f;
        float e[4][4];
        #pragma unroll
        for (int ut = 0; ut < 4; ++ut)
            #pragma unroll
            for (int r = 0; r < 4; ++r) {
                e[ut][r] = __expf((s[ut][r] - m) * SCALE);
                sum += e[ut][r];
            }
        sum += __shfl_xor(sum, 16);
        sum += __shfl_xor(sum, 32);
        float pinv = 1.0f / sum;
        #pragma unroll
        for (int ut = 0; ut < 4; ++ut) {
            int u0 = 16 * ut + 4 * lg;
            int2 v;
            v.x = pack2(e[ut][0] * pinv, e[ut][1] * pinv);
            v.y = pack2(e[ut][2] * pinv, e[ut][3] * pinv);
            *(int2*)(Pb + t * 128 + ((2 * u0) ^ ((t & 7) << 4))) = v;
        }
        #pragma unroll
        for (int j = 0; j < 8; ++j) {
            int ci = j * 256 + tid, n = ci >> 4, pos = ci & 15;
            *(int4*)(Wt + n * 256 + ((pos * 16) ^ ((n & 7) << 4))) = wreg[j];
        }
    }
    __syncthreads();

    {   // phase 3: V^T
        f32x4 vacc[8] = {};
        #pragma unroll
        for (int ks = 0; ks < 4; ++ks) {
            int k = ks * 32 + lg * 8;
            bfrag ax = ld256(Xb, t, k);
            #pragma unroll
            for (int ct = 0; ct < 8; ++ct) {
                bfrag bw = ld256(Wt, 16 * ct + lr, k);
                vacc[ct] = MFMA16(ax, bw, vacc[ct], 0, 0, 0);
            }
        }
        #pragma unroll
        for (int ct = 0; ct < 8; ++ct) {
            int c = 16 * ct + lr;
            int u0 = 16 * wid + 4 * lg;
            int2 v; v.x = pack2(vacc[ct][0], vacc[ct][1]); v.y = pack2(vacc[ct][2], vacc[ct][3]);
            *(int2*)(Vt + c * 128 + ((2 * u0) ^ ((c & 7) << 4))) = v;
        }
    }
    __syncthreads();

    float yl[8][4];
    {   // phase 4: Y^T = Vt x P ; yl = Y*X
        int4 wreg[8];
        const int4* wsrc = (const int4*)G1tB;
        #pragma unroll
        for (int j = 0; j < 8; ++j) wreg[j] = wsrc[j * 256 + tid];

        f32x4 y[8] = {};
        #pragma unroll
        for (int us = 0; us < 2; ++us) {
            int u = us * 32 + lg * 8;
            bfrag bp = ld128(Pb, t, u);
            #pragma unroll
            for (int ct = 0; ct < 8; ++ct) {
                bfrag av = ld128(Vt, 16 * ct + lr, u);
                y[ct] = MFMA16(av, bp, y[ct], 0, 0, 0);
            }
        }
        char* ylb = XMb;
        #pragma unroll
        for (int ct = 0; ct < 8; ++ct) {
            int c0 = 16 * ct + 4 * lg;
            int2 xw = *(const int2*)(Xb + t * 256 + ((2 * c0) ^ ((t & 7) << 4)));
            float x0 = b2f((unsigned short)(xw.x & 0xffff));
            float x1 = b2f((unsigned short)((unsigned)xw.x >> 16));
            float x2 = b2f((unsigned short)(xw.y & 0xffff));
            float x3 = b2f((unsigned short)((unsigned)xw.y >> 16));
            yl[ct][0] = y[ct][0] * x0;
            yl[ct][1] = y[ct][1] * x1;
            yl[ct][2] = y[ct][2] * x2;
            yl[ct][3] = y[ct][3] * x3;
            int2 v; v.x = pack2(yl[ct][0], yl[ct][1]); v.y = pack2(yl[ct][2], yl[ct][3]);
            *(int2*)(ylb + t * 256 + ((2 * c0) ^ ((t & 7) << 4))) = v;
        }
        #pragma unroll
        for (int j = 0; j < 8; ++j) {
            int ci = j * 256 + tid, n = ci >> 4, pos = ci & 15;
            *(int4*)(Wt + n * 256 + ((pos * 16) ^ ((n & 7) << 4))) = wreg[j];
        }
    }
    __syncthreads();

    {   // phase 5: gate + blend + store
        const char* ylb = XMb;
        f32x4 g[8] = {};
        #pragma unroll
        for (int ks = 0; ks < 4; ++ks) {
            int k = ks * 32 + lg * 8;
            bfrag byl = ld256(ylb, t, k);
            #pragma unroll
            for (int nt = 0; nt < 8; ++nt) {
                bfrag ag = ld256(Wt, 16 * nt + lr, k);
                g[nt] = MFMA16(ag, byl, g[nt], 0, 0, 0);
            }
        }
        #pragma unroll
        for (int nt = 0; nt < 8; ++nt) {
            #pragma unroll
            for (int r = 0; r < 4; ++r) {
                int c = 16 * nt + 4 * lg + r;
                float a = 1.0f / (1.0f + __expf(-(g[nt][r] + g0s[c])));
                float yv = a * ygs[c] + (1.0f - a) * yl[nt][r];
                out[obase + (size_t)(b * 128 + c) * HW + p0 + t] = yv;
            }
        }
    }
}

// ---------- K6/K7: conv3x3(128->512) + PixelShuffle + residual, MFMA fp16 ----
// Tile: 4 rows x 32 cols (M=128 px), N=256 oc, 4 waves x acc[8][4].
// Weight double-buffer: ds_write(slice k+1); issue load(slice k+2); compute k;
// barrier  -> prefetch latency hidden under compute, not drained cold.
template <int H, int W>
__global__ __launch_bounds__(256, 2) void k_conv_mfma(
    const float* __restrict__ in, const _Float16* __restrict__ Wcv,
    float* __restrict__ out) {
    constexpr int TXN = W / 32;
    int tile = blockIdx.x;
    int ty = tile / TXN, tx = tile % TXN;
    int y0 = ty * 4, x0 = tx * 32;
    int ob = blockIdx.y * 256;
    int b = blockIdx.z;

    __shared__ __align__(16) char sXs[16384];    // 204 rows x 80B, slot swz (row>>3)&1
    __shared__ __align__(16) char sW[2][16384];  // 256 oc x 64B, slot swz (row>>2)&3

    int tid = threadIdx.x;
    int wid = tid >> 6, lane = tid & 63;
    int lr = lane & 15, lg = lane >> 4;

    f32x4 acc[8][4] = {};

    int sy = tid / 34, sx = tid - sy * 34;
    int gy = y0 + sy - 1, gx = x0 + sx - 1;
    bool act = tid < 204;
    bool ok = act && gy >= 0 && gy < H && gx >= 0 && gx < W;
    const float* gp = in + (size_t)b * 128 * H * W + (size_t)gy * W + gx;
    int xswz = (tid >> 3) & 1;

    const int4* wsrc0 = (const int4*)(Wcv + (size_t)ob * 32);  // +2048 int4 per slice

    int4 wreg[4];
    #pragma unroll
    for (int j = 0; j < 4; ++j) wreg[j] = wsrc0[j * 256 + tid];

    // prologue: stage input slice 0, weights slice 0 -> buf0, load slice 1
    if (act) {
        float xv[32];
        if (ok) {
            #pragma unroll
            for (int ic = 0; ic < 32; ++ic) xv[ic] = gp[(size_t)ic * H * W];
        } else {
            #pragma unroll
            for (int ic = 0; ic < 32; ++ic) xv[ic] = 0.f;
        }
        #pragma unroll
        for (int s = 0; s < 4; ++s) {
            _Float16 hh[8];
            #pragma unroll
            for (int e = 0; e < 8; ++e) hh[e] = (_Float16)xv[s * 8 + e];
            *(int4*)(sXs + tid * 80 + ((s ^ xswz) << 4)) = *(int4*)hh;
        }
    }
    #pragma unroll
    for (int j = 0; j < 4; ++j) *(int4*)(sW[0] + (j * 256 + tid) * 16) = wreg[j];
    #pragma unroll
    for (int j = 0; j < 4; ++j) wreg[j] = wsrc0[2048 + j * 256 + tid];
    __syncthreads();

    int kg = 0;
    for (int ics = 0; ics < 4; ++ics) {
        if (ics) {
            if (act) {
                float xv[32];
                if (ok) {
                    #pragma unroll
                    for (int ic = 0; ic < 32; ++ic)
                        xv[ic] = gp[(size_t)(ics * 32 + ic) * H * W];
                } else {
                    #pragma unroll
                    for (int ic = 0; ic < 32; ++ic) xv[ic] = 0.f;
                }
                #pragma unroll
                for (int s = 0; s < 4; ++s) {
                    _Float16 hh[8];
                    #pragma unroll
                    for (int e = 0; e < 8; ++e) hh[e] = (_Float16)xv[s * 8 + e];
                    *(int4*)(sXs + tid * 80 + ((s ^ xswz) << 4)) = *(int4*)hh;
                }
            }
            __syncthreads();
        }
        for (int tap = 0; tap < 9; ++tap, ++kg) {
            if (kg < 35) {
                char* Wb = sW[(kg + 1) & 1];
                #pragma unroll
                for (int j = 0; j < 4; ++j)
                    *(int4*)(Wb + (j * 256 + tid) * 16) = wreg[j];
            }
            if (kg < 34) {
                #pragma unroll
                for (int j = 0; j < 4; ++j)
                    wreg[j] = wsrc0[(size_t)(kg + 2) * 2048 + j * 256 + tid];
            }
            const char* Wb = sW[kg & 1];
            hfrag af[4], bf[8];
            #pragma unroll
            for (int n = 0; n < 4; ++n) {
                int row = (wid * 4 + n) * 16 + lr;
                af[n] = *(const hfrag*)(Wb + row * 64 + ((lg ^ ((row >> 2) & 3)) << 4));
            }
            int dy = tap / 3, dx = tap - dy * 3;
            #pragma unroll
            for (int m = 0; m < 8; ++m) {
                int row = ((m >> 1) + dy) * 34 + (m & 1) * 16 + lr + dx;
                bf[m] = *(const hfrag*)(sXs + row * 80 + ((lg ^ ((row >> 3) & 1)) << 4));
            }
            #pragma unroll
            for (int m = 0; m < 8; ++m)
                #pragma unroll
                for (int n = 0; n < 4; ++n)
                    acc[m][n] = MFMA16H(af[n], bf[m], acc[m][n], 0, 0, 0);
            __syncthreads();
        }
    }

    // epilogue: PixelShuffle-fused residual RMW; adjacent 128B pairs per row
    float* outb = out + (size_t)b * 128 * 4 * H * W;
    #pragma unroll
    for (int n = 0; n < 4; ++n) {
        int oc0 = ob + (wid * 4 + n) * 16 + lg * 4;
        int c = oc0 >> 2;
        #pragma unroll
        for (int mr = 0; mr < 4; ++mr) {
            int py = y0 + mr;
            #pragma unroll
            for (int i2 = 0; i2 < 2; ++i2) {
                size_t rowb = ((size_t)c * (2 * H) + 2 * py + i2) * (2 * W);
                float2* p0 = (float2*)(outb + rowb + 2 * (x0 + lr));
                float2 v0 = *p0;
                v0.x += acc[2 * mr][n][i2 * 2 + 0];
                v0.y += acc[2 * mr][n][i2 * 2 + 1];
                *p0 = v0;
                float2* p1 = (float2*)(outb + rowb + 2 * (x0 + 16 + lr));
                float2 v1 = *p1;
                v1.x += acc[2 * mr + 1][n][i2 * 2 + 0];
                v1.y += acc[2 * mr + 1][n][i2 * 2 + 1];
                *p1 = v1;
            }
        }
    }
}

extern "C" void kernel_launch(void* const* d_in, const int* in_sizes, int n_in,
                              void* d_out, int out_size, void* d_ws, size_t ws_size,
                              hipStream_t stream) {
    const float* f0 = (const float*)d_in[0];
    const float* f1 = (const float*)d_in[1];
    const float* f2 = (const float*)d_in[2];
    const float* Wq = (const float*)d_in[3];
    const float* Wk = (const float*)d_in[4];
    const float* Wv = (const float*)d_in[5];
    const float* Wql = (const float*)d_in[6];
    const float* Wkl = (const float*)d_in[7];
    const float* Wvl = (const float*)d_in[8];
    const float* gate_w = (const float*)d_in[9];
    const float* conv0 = (const float*)d_in[10];
    const float* conv1 = (const float*)d_in[11];
    float* out = (float*)d_out;
    float* ws = (float*)d_ws;

    float* Mglob = ws;                    // 16384 f32
    float* ctr = Mglob + 16384;           // 688128 f32
    float* ycen = ctr + 688128;           // 688128 f32
    unsigned short* MtB = (unsigned short*)(ycen + 688128);  // 16384 bf16
    unsigned short* WvltB = MtB + 16384;                     // 16384 bf16
    unsigned short* G1tB = WvltB + 16384;                    // 16384 bf16
    _Float16* Wcv0 = (_Float16*)(G1tB + 16384);              // 589824 f16
    _Float16* Wcv1 = Wcv0 + 589824;                          // 589824 f16
    unsigned short* ctrb = (unsigned short*)(Wcv1 + 589824); // 688128 bf16
    unsigned short* Tgb = ctrb + 688128;                     // 688128 bf16
    unsigned short* Vgt = Tgb + 688128;                      // 4*128*NP bf16
    unsigned short* Pg = Vgt + 4 * 128 * NP;                 // 4*NWIN*NP bf16

    hipFuncSetAttribute((const void*)k_local_mfma,
                        hipFuncAttributeMaxDynamicSharedMemorySize, SMEM_SZ);
    hipFuncSetAttribute((const void*)k_qk,
                        hipFuncAttributeMaxDynamicSharedMemorySize, 32 * 1344 * 2);

    k_mm<<<dim3(128), 128, 0, stream>>>(Wq, Wk, Mglob);
    k_prep<<<dim3(128, 3), 128, 0, stream>>>(Wql, Wkl, Wvl, gate_w, MtB, WvltB, G1tB);
    k_prep_conv<<<dim3(2304, 2), 256, 0, stream>>>(conv0, conv1, Wcv0, Wcv1);
    k_centers<<<dim3(NWIN, 4), 256, 0, stream>>>(f0, f1, f2, ctr, ctrb);
    k_tgvg<<<dim3(NWIN, 4), 128, 0, stream>>>(ctr, Mglob, Wv, Tgb, Vgt);
    k_qk<<<dim3(NWIN / 32, 4), 256, 32 * 1344 * 2, stream>>>(Tgb, ctrb, Pg);
    k_pv<<<dim3(NWIN / 32, 4), 256, 0, stream>>>(Pg, Vgt, ctr, ycen);
    k_local_mfma<<<dim3(NWIN, 4), 256, SMEM_SZ, stream>>>(
        f0, f1, f2, MtB, WvltB, G1tB, gate_w, ycen, out);
    k_conv_mfma<64, 64><<<dim3(32, 2, 4), 256, 0, stream>>>(out + OUT0, Wcv0, out + OUT1);
    k_conv_mfma<128, 128><<<dim3(128, 2, 4), 256, 0, stream>>>(out + OUT1, Wcv1, out + OUT2);
}